// Round 3
// baseline (641.646 us; speedup 1.0000x reference)
//
#include <hip/hip_runtime.h>
#include <math.h>

typedef unsigned short u16;
typedef unsigned int   u32;
typedef __attribute__((ext_vector_type(8))) short bf16x8;
typedef __attribute__((ext_vector_type(4))) float f32x4;
typedef __attribute__((ext_vector_type(4))) int i32x4;

#define TTOT  2052
#define NPERS 4
#define LSEQ  2048
#define WIN   128
#define NHEAD 16
#define HDIM  64
#define DM    1024

__device__ __forceinline__ float bf2f(u16 u) {
    union { unsigned int i; float f; } v; v.i = ((unsigned int)u) << 16; return v.f;
}
__device__ __forceinline__ u16 f2bf(float f) {
    union { float f; unsigned int i; } v; v.f = f;
    unsigned int r = (v.i + 0x7fffu + ((v.i >> 16) & 1u)) >> 16;
    return (u16)r;
}
__device__ __forceinline__ u32 pk2(float lo, float hi) {
    return (u32)f2bf(lo) | ((u32)f2bf(hi) << 16);
}

// Stage 16 contiguous elements from global into LDS as bf16.
// F32: source is fp32 (convert); else source is bf16 (copy).
template<bool F32>
__device__ __forceinline__ void stage16(const void* src, u16* dst) {
    if (F32) {
        const f32x4* s = (const f32x4*)src;
        f32x4 a = s[0], b = s[1], c = s[2], d = s[3];
        i32x4 lo, hi;
        lo[0] = (int)pk2(a[0], a[1]); lo[1] = (int)pk2(a[2], a[3]);
        lo[2] = (int)pk2(b[0], b[1]); lo[3] = (int)pk2(b[2], b[3]);
        hi[0] = (int)pk2(c[0], c[1]); hi[1] = (int)pk2(c[2], c[3]);
        hi[2] = (int)pk2(d[0], d[1]); hi[3] = (int)pk2(d[2], d[3]);
        ((i32x4*)dst)[0] = lo;
        ((i32x4*)dst)[1] = hi;
    } else {
        const i32x4* s = (const i32x4*)src;
        ((i32x4*)dst)[0] = s[0];
        ((i32x4*)dst)[1] = s[1];
    }
}
__device__ __forceinline__ void stage16_zero(u16* dst) {
    i32x4 z = (i32x4){0,0,0,0};
    ((i32x4*)dst)[0] = z;
    ((i32x4*)dst)[1] = z;
}

// ---------------- GEMM core: C[M x 1024] = A[M x 1024] * Bt^T ----------------
// Bt is [1024 x 1024] row-major (n, k)  (the "@ W.T" pattern).
// If PM != nullptr, A is the virtual concat [PM(4 rows); X(M-4 rows)].
// OF32: write fp32 to C; else write bf16.
template<bool AF32, bool BF32, bool OF32>
__device__ __forceinline__ void gemm_core(const void* __restrict__ Xv, const void* __restrict__ PMv,
                                          int M, const void* __restrict__ Btv, void* __restrict__ Cv)
{
    __shared__ __align__(16) u16 As[128 * 40];  // stride 40 (pad 8): 16B-aligned rows, breaks conflicts
    __shared__ __align__(16) u16 Bs[128 * 40];
    const int tid  = threadIdx.x;
    const int wave = tid >> 6;
    const int lane = tid & 63;
    const int l15  = lane & 15;
    const int quad = lane >> 4;
    const int wm   = (wave >> 1) * 64;
    const int wn   = (wave & 1) * 64;
    const int Mb   = blockIdx.x * 128;
    const int Nb   = blockIdx.y * 128;

    const int ar  = tid >> 1;          // tile row this thread stages (0..127)
    const int ac  = (tid & 1) * 16;    // col chunk 0 or 16
    const int m_g = Mb + ar;

    const float* Xf  = (const float*)Xv;
    const u16*   Xh  = (const u16*)Xv;
    const float* PMf = (const float*)PMv;
    const float* Btf = (const float*)Btv;
    const u16*   Bth = (const u16*)Btv;

    f32x4 acc[4][4];
    #pragma unroll
    for (int i = 0; i < 4; i++)
        #pragma unroll
        for (int j = 0; j < 4; j++) acc[i][j] = (f32x4){0.f, 0.f, 0.f, 0.f};

    for (int kk = 0; kk < DM; kk += 32) {
        // ---- stage A tile (bounds-checked / virtual concat of PM rows + X rows) ----
        u16* adst = &As[ar * 40 + ac];
        if (PMv) {
            if (m_g < NPERS)      stage16<true>(PMf + (size_t)m_g * DM + kk + ac, adst);
            else if (m_g < M)     stage16<AF32>(AF32 ? (const void*)(Xf + (size_t)(m_g - NPERS) * DM + kk + ac)
                                                     : (const void*)(Xh + (size_t)(m_g - NPERS) * DM + kk + ac), adst);
            else                  stage16_zero(adst);
        } else {
            if (m_g < M)          stage16<AF32>(AF32 ? (const void*)(Xf + (size_t)m_g * DM + kk + ac)
                                                     : (const void*)(Xh + (size_t)m_g * DM + kk + ac), adst);
            else                  stage16_zero(adst);
        }
        // ---- stage B tile (always in bounds: N=K=1024) ----
        stage16<BF32>(BF32 ? (const void*)(Btf + (size_t)(Nb + ar) * DM + kk + ac)
                           : (const void*)(Bth + (size_t)(Nb + ar) * DM + kk + ac),
                      &Bs[ar * 40 + ac]);
        __syncthreads();

        bf16x8 af[4], bfv[4];
        #pragma unroll
        for (int t = 0; t < 4; t++) af[t]  = *(const bf16x8*)&As[(wm + t*16 + l15) * 40 + quad * 8];
        #pragma unroll
        for (int t = 0; t < 4; t++) bfv[t] = *(const bf16x8*)&Bs[(wn + t*16 + l15) * 40 + quad * 8];
        #pragma unroll
        for (int tm = 0; tm < 4; tm++)
            #pragma unroll
            for (int tn = 0; tn < 4; tn++)
                acc[tm][tn] = __builtin_amdgcn_mfma_f32_16x16x32_bf16(af[tm], bfv[tn], acc[tm][tn], 0, 0, 0);
        __syncthreads();
    }

    // epilogue: D col(n) = lane&15, row(m) = quad*4 + r
    #pragma unroll
    for (int tm = 0; tm < 4; tm++) {
        const int mb = Mb + wm + tm * 16 + quad * 4;
        #pragma unroll
        for (int tn = 0; tn < 4; tn++) {
            const int n = Nb + wn + tn * 16 + l15;
            #pragma unroll
            for (int r = 0; r < 4; r++) {
                const int m = mb + r;
                if (m < M) {
                    if (OF32) ((float*)Cv)[(size_t)m * DM + n] = acc[tm][tn][r];
                    else      ((u16*)Cv)[(size_t)m * DM + n]   = f2bf(acc[tm][tn][r]);
                }
            }
        }
    }
}

__global__ __launch_bounds__(256) void gemm_qkv(const float* __restrict__ x, const float* __restrict__ pm,
    const float* __restrict__ Wq, const float* __restrict__ Wk, const float* __restrict__ Wv,
    u16* __restrict__ Qr, u16* __restrict__ Kr, u16* __restrict__ Vr)
{
    const float* W; u16* Cc;
    if (blockIdx.z == 0)      { W = Wq; Cc = Qr; }
    else if (blockIdx.z == 1) { W = Wk; Cc = Kr; }
    else                      { W = Wv; Cc = Vr; }
    gemm_core<true, true, false>(x, pm, TTOT, W, Cc);
}

__global__ __launch_bounds__(256) void gemm_out(const u16* __restrict__ AO, const float* __restrict__ Wo,
                                                float* __restrict__ C)
{
    gemm_core<false, true, true>(AO, nullptr, LSEQ, Wo, C);
}

// ---------------- depthwise causal conv (K=3) + bias + SiLU + optional l2norm ----------------
// out[t,d] = silu(w0*raw[t-2,d] + w1*raw[t-1,d] + w2*raw[t,d] + b[d]); Q/K rows then / max(||row||,eps)
__global__ __launch_bounds__(256) void conv_silu_norm(
    const u16* __restrict__ Qr, const u16* __restrict__ Kr, const u16* __restrict__ Vr,
    const float* __restrict__ qw, const float* __restrict__ qb,
    const float* __restrict__ kw, const float* __restrict__ kb,
    const float* __restrict__ vw, const float* __restrict__ vb,
    u16* __restrict__ Qc, u16* __restrict__ Kc, u16* __restrict__ Vc)
{
    const int t = blockIdx.x;   // 0..2051
    const int z = blockIdx.y;   // 0:Q 1:K 2:V
    const u16* raw; const float *w, *b; u16* out;
    if (z == 0)      { raw = Qr; w = qw; b = qb; out = Qc; }
    else if (z == 1) { raw = Kr; w = kw; b = kb; out = Kc; }
    else             { raw = Vr; w = vw; b = vb; out = Vc; }

    const int tid = threadIdx.x;
    float vals[4];
    float ss = 0.f;
    #pragma unroll
    for (int j = 0; j < 4; j++) {
        const int d = tid + j * 256;
        float acc = b[d];
        acc += w[d*3 + 2] * bf2f(raw[(size_t)t * DM + d]);
        if (t >= 1) acc += w[d*3 + 1] * bf2f(raw[(size_t)(t-1) * DM + d]);
        if (t >= 2) acc += w[d*3 + 0] * bf2f(raw[(size_t)(t-2) * DM + d]);
        const float y = acc / (1.f + expf(-acc));   // silu
        vals[j] = y;
        ss += y * y;
    }
    float inv = 1.f;
    if (z < 2) {
        #pragma unroll
        for (int off = 32; off > 0; off >>= 1) ss += __shfl_down(ss, off, 64);
        __shared__ float red[4];
        const int wv = tid >> 6, ln = tid & 63;
        if (ln == 0) red[wv] = ss;
        __syncthreads();
        const float tot = red[0] + red[1] + red[2] + red[3];
        inv = 1.f / fmaxf(sqrtf(tot), 1e-12f);
    }
    #pragma unroll
    for (int j = 0; j < 4; j++) {
        const int d = tid + j * 256;
        out[(size_t)t * DM + d] = f2bf(vals[j] * inv);
    }
}

// ---------------- sliding-window attention, 1 wave per (query, head) ----------------
__global__ __launch_bounds__(64) void attn(const u16* __restrict__ Q, const u16* __restrict__ K,
                                           const u16* __restrict__ V, u16* __restrict__ AO)
{
    const int q    = blockIdx.x;         // 0..2047 (sequence rows only)
    const int h    = blockIdx.y;
    const int tq   = q + NPERS;
    const int lane = threadIdx.x;
    const int wstart = max(NPERS, tq - WIN + 1);
    const int nk   = NPERS + (tq - wstart + 1);   // <= 132

    __shared__ __align__(4) u16 Ks[132 * 66];     // stride 66 -> only 2-way (free) bank aliasing
    __shared__ float Qs[64];
    __shared__ float Ps[132];

    Qs[lane] = bf2f(Q[(size_t)tq * DM + h * HDIM + lane]);

    // stage K rows: two rows per iteration, 32 lanes x ushort2 each
    const int half = lane >> 5, l32 = lane & 31;
    for (int i = half; i < nk; i += 2) {
        const int row = (i < NPERS) ? i : (wstart + i - NPERS);
        const u32 v = *(const u32*)&K[(size_t)row * DM + h * HDIM + l32 * 2];
        *(u32*)&Ks[i * 66 + l32 * 2] = v;
    }
    __syncthreads();

    const float scale = 0.125f;  // 64^-0.5
    float s0 = 0.f, s1 = 0.f, s2 = 0.f;
    #pragma unroll 8
    for (int d = 0; d < HDIM; d++) {
        const float qd = Qs[d];
        s0 += qd * bf2f(Ks[lane * 66 + d]);
        s1 += qd * bf2f(Ks[(lane + 64) * 66 + d]);
    }
    if (lane < 4) {
        #pragma unroll 8
        for (int d = 0; d < HDIM; d++) s2 += Qs[d] * bf2f(Ks[(lane + 128) * 66 + d]);
    }
    const bool v0 = (lane < nk);
    const bool v1 = (lane + 64 < nk);
    const bool v2 = (lane < 4) && (lane + 128 < nk);
    s0 *= scale; s1 *= scale; s2 *= scale;

    float mx = -INFINITY;
    if (v0) mx = fmaxf(mx, s0);
    if (v1) mx = fmaxf(mx, s1);
    if (v2) mx = fmaxf(mx, s2);
    #pragma unroll
    for (int off = 32; off > 0; off >>= 1) mx = fmaxf(mx, __shfl_xor(mx, off, 64));

    const float e0 = v0 ? expf(s0 - mx) : 0.f;
    const float e1 = v1 ? expf(s1 - mx) : 0.f;
    const float e2 = v2 ? expf(s2 - mx) : 0.f;
    float sum = e0 + e1 + e2;
    #pragma unroll
    for (int off = 32; off > 0; off >>= 1) sum += __shfl_xor(sum, off, 64);
    const float inv = 1.f / sum;

    if (v0) Ps[lane]       = e0 * inv;
    if (v1) Ps[lane + 64]  = e1 * inv;
    if (v2) Ps[lane + 128] = e2 * inv;
    __syncthreads();

    // PV: lane = output dim d; V read straight from global (coalesced 128B/row, cache-resident)
    float acc = 0.f;
    for (int i = 0; i < nk; i++) {
        const int row = (i < NPERS) ? i : (wstart + i - NPERS);
        acc += Ps[i] * bf2f(V[(size_t)row * DM + h * HDIM + lane]);
    }
    AO[(size_t)q * DM + h * HDIM + lane] = f2bf(acc);
}

extern "C" void kernel_launch(void* const* d_in, const int* in_sizes, int n_in,
                              void* d_out, int out_size, void* d_ws, size_t ws_size,
                              hipStream_t stream)
{
    const float* x  = (const float*)d_in[0];
    const float* pm = (const float*)d_in[1];
    const float* Wq = (const float*)d_in[2];
    const float* Wk = (const float*)d_in[3];
    const float* Wv = (const float*)d_in[4];
    const float* Wo = (const float*)d_in[5];
    const float* qw = (const float*)d_in[6];
    const float* qb = (const float*)d_in[7];
    const float* kw = (const float*)d_in[8];
    const float* kb = (const float*)d_in[9];
    const float* vw = (const float*)d_in[10];
    const float* vb = (const float*)d_in[11];
    float* out = (float*)d_out;    // reference output dtype is float32

    const size_t R = (size_t)TTOT * DM;          // 2,101,248 elements
    u16* Qr = (u16*)d_ws;
    u16* Kr = Qr + R;
    u16* Vr = Kr + R;
    u16* Qc = Vr + R;
    u16* Kc = Qc + R;
    u16* Vc = Kc + R;
    u16* AO = Vc + R;                            // 2048*1024; total ~29.4 MB

    // 1) QKV projections: [2052,1024] @ W.T for q,k,v (fp32 in -> bf16 staged MFMA)
    hipLaunchKernelGGL(gemm_qkv, dim3(17, 8, 3), dim3(256), 0, stream,
                       x, pm, Wq, Wk, Wv, Qr, Kr, Vr);
    // 2) causal depthwise conv + SiLU + l2norm(Q,K)  (fp32 weights)
    hipLaunchKernelGGL(conv_silu_norm, dim3(TTOT, 3), dim3(256), 0, stream,
                       Qr, Kr, Vr, qw, qb, kw, kb, vw, vb, Qc, Kc, Vc);
    // 3) sliding-window attention (sequence rows only)
    hipLaunchKernelGGL(attn, dim3(LSEQ, NHEAD), dim3(64), 0, stream, Qc, Kc, Vc, AO);
    // 4) output projection into d_out (bf16 A, fp32 B, fp32 out)
    hipLaunchKernelGGL(gemm_out, dim3(16, 8, 1), dim3(256), 0, stream, AO, Wo, out);
}

// Round 4
// 229.390 us; speedup vs baseline: 2.7972x; 2.7972x over previous
//
#include <hip/hip_runtime.h>
#include <math.h>

typedef unsigned short u16;
typedef unsigned int   u32;
typedef unsigned long long u64;
typedef __attribute__((ext_vector_type(8))) short bf16x8;
typedef __attribute__((ext_vector_type(4))) float f32x4;
typedef __attribute__((ext_vector_type(4))) int i32x4;

#define TTOT  2052
#define NPERS 4
#define LSEQ  2048
#define WIN   128
#define NHEAD 16
#define HDIM  64
#define DM    1024

__device__ __forceinline__ float bf2f(u16 u) {
    union { unsigned int i; float f; } v; v.i = ((unsigned int)u) << 16; return v.f;
}
__device__ __forceinline__ u16 f2bf(float f) {
    union { float f; unsigned int i; } v; v.f = f;
    unsigned int r = (v.i + 0x7fffu + ((v.i >> 16) & 1u)) >> 16;
    return (u16)r;
}
__device__ __forceinline__ u32 pk2(float lo, float hi) {
    return (u32)f2bf(lo) | ((u32)f2bf(hi) << 16);
}

template<bool F32>
__device__ __forceinline__ void stage16(const void* src, u16* dst) {
    if (F32) {
        const f32x4* s = (const f32x4*)src;
        f32x4 a = s[0], b = s[1], c = s[2], d = s[3];
        i32x4 lo, hi;
        lo[0] = (int)pk2(a[0], a[1]); lo[1] = (int)pk2(a[2], a[3]);
        lo[2] = (int)pk2(b[0], b[1]); lo[3] = (int)pk2(b[2], b[3]);
        hi[0] = (int)pk2(c[0], c[1]); hi[1] = (int)pk2(c[2], c[3]);
        hi[2] = (int)pk2(d[0], d[1]); hi[3] = (int)pk2(d[2], d[3]);
        ((i32x4*)dst)[0] = lo;
        ((i32x4*)dst)[1] = hi;
    } else {
        const i32x4* s = (const i32x4*)src;
        ((i32x4*)dst)[0] = s[0];
        ((i32x4*)dst)[1] = s[1];
    }
}
__device__ __forceinline__ void stage16_zero(u16* dst) {
    i32x4 z = (i32x4){0,0,0,0};
    ((i32x4*)dst)[0] = z;
    ((i32x4*)dst)[1] = z;
}

// ---------------- GEMM core: C[M x 1024] = A[M x 1024] * Bt^T ----------------
template<bool AF32, bool BF32, bool OF32>
__device__ __forceinline__ void gemm_core(const void* __restrict__ Xv, const void* __restrict__ PMv,
                                          int M, const void* __restrict__ Btv, void* __restrict__ Cv)
{
    __shared__ __align__(16) u16 As[128 * 40];
    __shared__ __align__(16) u16 Bs[128 * 40];
    const int tid  = threadIdx.x;
    const int wave = tid >> 6;
    const int lane = tid & 63;
    const int l15  = lane & 15;
    const int quad = lane >> 4;
    const int wm   = (wave >> 1) * 64;
    const int wn   = (wave & 1) * 64;
    const int Mb   = blockIdx.x * 128;
    const int Nb   = blockIdx.y * 128;

    const int ar  = tid >> 1;
    const int ac  = (tid & 1) * 16;
    const int m_g = Mb + ar;

    const float* Xf  = (const float*)Xv;
    const u16*   Xh  = (const u16*)Xv;
    const float* PMf = (const float*)PMv;
    const float* Btf = (const float*)Btv;
    const u16*   Bth = (const u16*)Btv;

    f32x4 acc[4][4];
    #pragma unroll
    for (int i = 0; i < 4; i++)
        #pragma unroll
        for (int j = 0; j < 4; j++) acc[i][j] = (f32x4){0.f, 0.f, 0.f, 0.f};

    for (int kk = 0; kk < DM; kk += 32) {
        u16* adst = &As[ar * 40 + ac];
        if (PMv) {
            if (m_g < NPERS)      stage16<true>(PMf + (size_t)m_g * DM + kk + ac, adst);
            else if (m_g < M)     stage16<AF32>(AF32 ? (const void*)(Xf + (size_t)(m_g - NPERS) * DM + kk + ac)
                                                     : (const void*)(Xh + (size_t)(m_g - NPERS) * DM + kk + ac), adst);
            else                  stage16_zero(adst);
        } else {
            if (m_g < M)          stage16<AF32>(AF32 ? (const void*)(Xf + (size_t)m_g * DM + kk + ac)
                                                     : (const void*)(Xh + (size_t)m_g * DM + kk + ac), adst);
            else                  stage16_zero(adst);
        }
        stage16<BF32>(BF32 ? (const void*)(Btf + (size_t)(Nb + ar) * DM + kk + ac)
                           : (const void*)(Bth + (size_t)(Nb + ar) * DM + kk + ac),
                      &Bs[ar * 40 + ac]);
        __syncthreads();

        bf16x8 af[4], bfv[4];
        #pragma unroll
        for (int t = 0; t < 4; t++) af[t]  = *(const bf16x8*)&As[(wm + t*16 + l15) * 40 + quad * 8];
        #pragma unroll
        for (int t = 0; t < 4; t++) bfv[t] = *(const bf16x8*)&Bs[(wn + t*16 + l15) * 40 + quad * 8];
        #pragma unroll
        for (int tm = 0; tm < 4; tm++)
            #pragma unroll
            for (int tn = 0; tn < 4; tn++)
                acc[tm][tn] = __builtin_amdgcn_mfma_f32_16x16x32_bf16(af[tm], bfv[tn], acc[tm][tn], 0, 0, 0);
        __syncthreads();
    }

    #pragma unroll
    for (int tm = 0; tm < 4; tm++) {
        const int mb = Mb + wm + tm * 16 + quad * 4;
        #pragma unroll
        for (int tn = 0; tn < 4; tn++) {
            const int n = Nb + wn + tn * 16 + l15;
            #pragma unroll
            for (int r = 0; r < 4; r++) {
                const int m = mb + r;
                if (m < M) {
                    if (OF32) ((float*)Cv)[(size_t)m * DM + n] = acc[tm][tn][r];
                    else      ((u16*)Cv)[(size_t)m * DM + n]   = f2bf(acc[tm][tn][r]);
                }
            }
        }
    }
}

__global__ __launch_bounds__(256) void gemm_qkv(const float* __restrict__ x, const float* __restrict__ pm,
    const float* __restrict__ Wq, const float* __restrict__ Wk, const float* __restrict__ Wv,
    u16* __restrict__ Qr, u16* __restrict__ Kr, u16* __restrict__ Vr)
{
    const float* W; u16* Cc;
    if (blockIdx.z == 0)      { W = Wq; Cc = Qr; }
    else if (blockIdx.z == 1) { W = Wk; Cc = Kr; }
    else                      { W = Wv; Cc = Vr; }
    gemm_core<true, true, false>(x, pm, TTOT, W, Cc);
}

__global__ __launch_bounds__(256) void gemm_out(const u16* __restrict__ AO, const float* __restrict__ Wo,
                                                float* __restrict__ C)
{
    gemm_core<false, true, true>(AO, nullptr, LSEQ, Wo, C);
}

// ---------------- depthwise causal conv (K=3) + bias + SiLU + optional l2norm ----------------
__global__ __launch_bounds__(256) void conv_silu_norm(
    const u16* __restrict__ Qr, const u16* __restrict__ Kr, const u16* __restrict__ Vr,
    const float* __restrict__ qw, const float* __restrict__ qb,
    const float* __restrict__ kw, const float* __restrict__ kb,
    const float* __restrict__ vw, const float* __restrict__ vb,
    u16* __restrict__ Qc, u16* __restrict__ Kc, u16* __restrict__ Vc)
{
    const int t = blockIdx.x;
    const int z = blockIdx.y;
    const u16* raw; const float *w, *b; u16* out;
    if (z == 0)      { raw = Qr; w = qw; b = qb; out = Qc; }
    else if (z == 1) { raw = Kr; w = kw; b = kb; out = Kc; }
    else             { raw = Vr; w = vw; b = vb; out = Vc; }

    const int tid = threadIdx.x;
    float vals[4];
    float ss = 0.f;
    #pragma unroll
    for (int j = 0; j < 4; j++) {
        const int d = tid + j * 256;
        float acc = b[d];
        acc += w[d*3 + 2] * bf2f(raw[(size_t)t * DM + d]);
        if (t >= 1) acc += w[d*3 + 1] * bf2f(raw[(size_t)(t-1) * DM + d]);
        if (t >= 2) acc += w[d*3 + 0] * bf2f(raw[(size_t)(t-2) * DM + d]);
        const float y = acc / (1.f + expf(-acc));
        vals[j] = y;
        ss += y * y;
    }
    float inv = 1.f;
    if (z < 2) {
        #pragma unroll
        for (int off = 32; off > 0; off >>= 1) ss += __shfl_down(ss, off, 64);
        __shared__ float red[4];
        const int wv = tid >> 6, ln = tid & 63;
        if (ln == 0) red[wv] = ss;
        __syncthreads();
        const float tot = red[0] + red[1] + red[2] + red[3];
        inv = 1.f / fmaxf(sqrtf(tot), 1e-12f);
    }
    #pragma unroll
    for (int j = 0; j < 4; j++) {
        const int d = tid + j * 256;
        out[(size_t)t * DM + d] = f2bf(vals[j] * inv);
    }
}

// ---------------- MFMA flash attention: 1 block = 1 head x 64 queries ----------------
#define QT     64
#define KTILES 13      // 13*16 = 208 key slots for QK
#define KROWS  208
#define KPAD   224     // PV k-extent: 7 steps of 32
#define KSTR   72      // Ks row stride (u16): 144B, 16B-aligned, 2-way banks
#define VSTR   232     // Vt/Ps row stride (u16): 464B, 16B-aligned, 2-way banks

__global__ __launch_bounds__(256) void attn(const u16* __restrict__ Q, const u16* __restrict__ K,
                                            const u16* __restrict__ V, u16* __restrict__ AO)
{
    const int h  = blockIdx.y;
    const int qb = blockIdx.x * QT;                       // first query (sequence space)
    const int kstart = max(NPERS, qb + NPERS - (WIN - 1));// first staged window row
    const int nk = NPERS + (qb + NPERS + QT - 1) - kstart + 1; // valid key slots (<=195)

    __shared__ __align__(16) u16 Ks[KROWS * KSTR];
    __shared__ __align__(16) u16 Vt[64 * VSTR];
    __shared__ __align__(16) u16 Ps[QT * VSTR];

    const int tid = threadIdx.x;

    // ---- stage K rows (slot -> global row: i<4 -> i, else kstart+i-4) ----
    for (int c = tid; c < KROWS * 8; c += 256) {
        const int i = c >> 3, off = (c & 7) * 8;
        if (i < nk) {
            const int g = (i < NPERS) ? i : (kstart + i - NPERS);
            *(i32x4*)&Ks[i * KSTR + off] = *(const i32x4*)&K[(size_t)g * DM + h * HDIM + off];
        }
    }
    // ---- stage V transposed (zero-padded to KPAD so 0*garbage can't NaN) ----
    {
        const int d = tid & 63, w4 = tid >> 6;
        for (int i2 = w4 * 2; i2 < KPAD; i2 += 8) {
            u16 a = 0, b = 0;
            if (i2 < nk)     { const int g = (i2     < NPERS) ? i2     : (kstart + i2     - NPERS); a = V[(size_t)g * DM + h * HDIM + d]; }
            if (i2 + 1 < nk) { const int g = (i2 + 1 < NPERS) ? i2 + 1 : (kstart + i2 + 1 - NPERS); b = V[(size_t)g * DM + h * HDIM + d]; }
            *(u32*)&Vt[d * VSTR + i2] = (u32)a | ((u32)b << 16);
        }
    }
    __syncthreads();

    const int wv = tid >> 6, lane = tid & 63, l15 = lane & 15, quad = lane >> 4;
    const int qloc0 = wv * 16;                     // block-local first query of this wave

    // Q A-fragments straight from global: lane row = query l15, k = d
    const int tqrow = qb + qloc0 + l15 + NPERS;
    const bf16x8 qa0 = *(const bf16x8*)&Q[(size_t)tqrow * DM + h * HDIM + quad * 8];
    const bf16x8 qa1 = *(const bf16x8*)&Q[(size_t)tqrow * DM + h * HDIM + 32 + quad * 8];

    // ---- QK^T: 13 score tiles in registers ----
    f32x4 st[KTILES];
    #pragma unroll
    for (int t = 0; t < KTILES; t++) {
        const bf16x8 kb0 = *(const bf16x8*)&Ks[(t * 16 + l15) * KSTR + quad * 8];
        const bf16x8 kb1 = *(const bf16x8*)&Ks[(t * 16 + l15) * KSTR + 32 + quad * 8];
        f32x4 z = (f32x4){0.f, 0.f, 0.f, 0.f};
        z = __builtin_amdgcn_mfma_f32_16x16x32_bf16(qa0, kb0, z, 0, 0, 0);
        z = __builtin_amdgcn_mfma_f32_16x16x32_bf16(qa1, kb1, z, 0, 0, 0);
        st[t] = z;
    }

    // ---- mask + scale, then per-row (query) softmax across all keys ----
    const float scale = 0.125f;  // 64^-0.5
    float mrow[4] = {-INFINITY, -INFINITY, -INFINITY, -INFINITY};
    #pragma unroll
    for (int t = 0; t < KTILES; t++) {
        const int i  = t * 16 + l15;          // key slot (same for all r)
        const int kg = kstart + i - NPERS;    // global row if window slot
        #pragma unroll
        for (int r = 0; r < 4; r++) {
            const int tqr = qb + qloc0 + quad * 4 + r + NPERS;
            const bool ok = (i < NPERS) || ((i < nk) && (kg >= tqr - (WIN - 1)) && (kg <= tqr));
            const float s = ok ? st[t][r] * scale : -INFINITY;
            st[t][r] = s;
            mrow[r] = fmaxf(mrow[r], s);
        }
    }
    #pragma unroll
    for (int off = 1; off < 16; off <<= 1)
        #pragma unroll
        for (int r = 0; r < 4; r++) mrow[r] = fmaxf(mrow[r], __shfl_xor(mrow[r], off, 64));

    float ssum[4] = {0.f, 0.f, 0.f, 0.f};
    #pragma unroll
    for (int t = 0; t < KTILES; t++)
        #pragma unroll
        for (int r = 0; r < 4; r++) {
            const float p = expf(st[t][r] - mrow[r]);
            st[t][r] = p;
            ssum[r] += p;
        }
    #pragma unroll
    for (int off = 1; off < 16; off <<= 1)
        #pragma unroll
        for (int r = 0; r < 4; r++) ssum[r] += __shfl_xor(ssum[r], off, 64);
    float inv[4];
    #pragma unroll
    for (int r = 0; r < 4; r++) inv[r] = 1.f / ssum[r];

    // ---- write P (bf16) to LDS; zero tail keys [208,224) ----
    #pragma unroll
    for (int t = 0; t < KTILES; t++)
        #pragma unroll
        for (int r = 0; r < 4; r++)
            Ps[(qloc0 + quad * 4 + r) * VSTR + t * 16 + l15] = f2bf(st[t][r] * inv[r]);
    *(u64*)&Ps[(qloc0 + l15) * VSTR + KROWS + quad * 4] = 0ULL;
    __syncthreads();

    // ---- PV: O[q,d] = sum_k P[q,k] V[k,d]; A = P rows(q), B = Vt rows(d) ----
    f32x4 oacc[4];
    #pragma unroll
    for (int dt = 0; dt < 4; dt++) oacc[dt] = (f32x4){0.f, 0.f, 0.f, 0.f};
    for (int ks = 0; ks < KPAD / 32; ks++) {
        const bf16x8 pa = *(const bf16x8*)&Ps[(qloc0 + l15) * VSTR + ks * 32 + quad * 8];
        #pragma unroll
        for (int dt = 0; dt < 4; dt++) {
            const bf16x8 vb = *(const bf16x8*)&Vt[(dt * 16 + l15) * VSTR + ks * 32 + quad * 8];
            oacc[dt] = __builtin_amdgcn_mfma_f32_16x16x32_bf16(pa, vb, oacc[dt], 0, 0, 0);
        }
    }

    // ---- write O: row(q) = quad*4+r, col(d) = dt*16 + l15 ----
    #pragma unroll
    for (int dt = 0; dt < 4; dt++)
        #pragma unroll
        for (int r = 0; r < 4; r++)
            AO[(size_t)(qb + qloc0 + quad * 4 + r) * DM + h * HDIM + dt * 16 + l15] = f2bf(oacc[dt][r]);
}

extern "C" void kernel_launch(void* const* d_in, const int* in_sizes, int n_in,
                              void* d_out, int out_size, void* d_ws, size_t ws_size,
                              hipStream_t stream)
{
    const float* x  = (const float*)d_in[0];
    const float* pm = (const float*)d_in[1];
    const float* Wq = (const float*)d_in[2];
    const float* Wk = (const float*)d_in[3];
    const float* Wv = (const float*)d_in[4];
    const float* Wo = (const float*)d_in[5];
    const float* qw = (const float*)d_in[6];
    const float* qb = (const float*)d_in[7];
    const float* kw = (const float*)d_in[8];
    const float* kb = (const float*)d_in[9];
    const float* vw = (const float*)d_in[10];
    const float* vb = (const float*)d_in[11];
    float* out = (float*)d_out;

    const size_t R = (size_t)TTOT * DM;
    u16* Qr = (u16*)d_ws;
    u16* Kr = Qr + R;
    u16* Vr = Kr + R;
    u16* Qc = Vr + R;
    u16* Kc = Qc + R;
    u16* Vc = Kc + R;
    u16* AO = Vc + R;

    hipLaunchKernelGGL(gemm_qkv, dim3(17, 8, 3), dim3(256), 0, stream,
                       x, pm, Wq, Wk, Wv, Qr, Kr, Vr);
    hipLaunchKernelGGL(conv_silu_norm, dim3(TTOT, 3), dim3(256), 0, stream,
                       Qr, Kr, Vr, qw, qb, kw, kb, vw, vb, Qc, Kc, Vc);
    hipLaunchKernelGGL(attn, dim3(LSEQ / QT, NHEAD), dim3(256), 0, stream, Qc, Kc, Vc, AO);
    hipLaunchKernelGGL(gemm_out, dim3(16, 8, 1), dim3(256), 0, stream, AO, Wo, out);
}

// Round 5
// 177.030 us; speedup vs baseline: 3.6245x; 1.2958x over previous
//
#include <hip/hip_runtime.h>
#include <math.h>

typedef unsigned short u16;
typedef unsigned int   u32;
typedef unsigned long long u64;
typedef __attribute__((ext_vector_type(8))) short bf16x8;
typedef __attribute__((ext_vector_type(4))) float f32x4;
typedef __attribute__((ext_vector_type(4))) int i32x4;

#define TTOT  2052
#define NPERS 4
#define LSEQ  2048
#define WIN   128
#define NHEAD 16
#define HDIM  64
#define DM    1024
#define MPAD  2112   // 33 * 64

__device__ __forceinline__ float bf2f(u16 u) {
    union { unsigned int i; float f; } v; v.i = ((unsigned int)u) << 16; return v.f;
}
__device__ __forceinline__ u16 f2bf(float f) {
    union { float f; unsigned int i; } v; v.f = f;
    unsigned int r = (v.i + 0x7fffu + ((v.i >> 16) & 1u)) >> 16;
    return (u16)r;
}
__device__ __forceinline__ u32 pk2(float lo, float hi) {
    return (u32)f2bf(lo) | ((u32)f2bf(hi) << 16);
}

// async global->LDS, 16B per lane; LDS dst = wave-uniform base + lane*16
__device__ __forceinline__ void glds16(const u16* g, u16* l) {
    __builtin_amdgcn_global_load_lds(
        (__attribute__((address_space(1))) void*)(g),
        (__attribute__((address_space(3))) void*)(l),
        16, 0, 0);
}

// ---------------- fp32 -> bf16 conversion / repack pass ----------------
// z=0: xp = [pm ; x] (2052 valid rows of MPAD); z=1..3: Wcat slices; z=4: Woh
__global__ __launch_bounds__(256) void cvt(const float* __restrict__ x, const float* __restrict__ pm,
    const float* __restrict__ Wq, const float* __restrict__ Wk, const float* __restrict__ Wv,
    const float* __restrict__ Wo,
    u16* __restrict__ xp, u16* __restrict__ Wcat, u16* __restrict__ Woh)
{
    const int z = blockIdx.y;
    const int u = blockIdx.x * 256 + threadIdx.x;   // unit = 4 floats
    if (z == 0) {
        if (u >= TTOT * 256) return;
        const size_t e = (size_t)u * 4;
        const int row = (int)(e >> 10), c = (int)(e & 1023);
        const float* s = (row < NPERS) ? (pm + (size_t)row * DM + c)
                                       : (x + (size_t)(row - NPERS) * DM + c);
        f32x4 v = *(const f32x4*)s;
        *(u64*)(xp + e) = (u64)pk2(v[0], v[1]) | ((u64)pk2(v[2], v[3]) << 32);
    } else {
        if (u >= 256 * DM) return;                  // 1024*1024/4 units
        const size_t e = (size_t)u * 4;
        const float* s; u16* d;
        if (z == 1)      { s = Wq + e; d = Wcat + e; }
        else if (z == 2) { s = Wk + e; d = Wcat + (size_t)DM * DM + e; }
        else if (z == 3) { s = Wv + e; d = Wcat + 2 * (size_t)DM * DM + e; }
        else             { s = Wo + e; d = Woh + e; }
        f32x4 v = *(const f32x4*)s;
        *(u64*)d = (u64)pk2(v[0], v[1]) | ((u64)pk2(v[2], v[3]) << 32);
    }
}

// ---------------- m97-style bf16 GEMM: C[tile] = A[TM x 1024] * B^T ----------------
// A, B row-major along K (both bf16). BK=32, global_load_lds staging, branch-free.
template<int TM, int TN, bool OF32>
__device__ __forceinline__ void gemm_lds(const u16* __restrict__ Ablk, const u16* __restrict__ Bblk,
                                         void* __restrict__ Cbase, int mlim)
{
    __shared__ __align__(16) u16 As[TM * 32];
    __shared__ __align__(16) u16 Bs[TN * 32];
    const int tid  = threadIdx.x;
    const int lane = tid & 63;
    const int l15  = lane & 15, quad = lane >> 4;
    constexpr int RM = TM / 32, RN = TN / 32;
    const int wm = (tid >> 7) * (TM / 2);           // wave row
    const int wn = ((tid >> 6) & 1) * (TN / 2);     // wave col
    const int wb = tid & 192;                        // wave * 64

    f32x4 acc[RM][RN];
    #pragma unroll
    for (int i = 0; i < RM; i++)
        #pragma unroll
        for (int j = 0; j < RN; j++) acc[i][j] = (f32x4){0.f, 0.f, 0.f, 0.f};

    constexpr int LA = (TM * 32) / 2048;   // 16B-loads per thread for A tile
    constexpr int LB = (TN * 32) / 2048;

    for (int kk = 0; kk < DM; kk += 32) {
        #pragma unroll
        for (int i = 0; i < LA; i++) {
            const int e = i * 256 + tid;           // 8-elem chunk index
            glds16(Ablk + (size_t)(e >> 2) * DM + kk + (e & 3) * 8,
                   As + (size_t)(i * 256 + wb) * 8);
        }
        #pragma unroll
        for (int i = 0; i < LB; i++) {
            const int e = i * 256 + tid;
            glds16(Bblk + (size_t)(e >> 2) * DM + kk + (e & 3) * 8,
                   Bs + (size_t)(i * 256 + wb) * 8);
        }
        __syncthreads();
        bf16x8 af[RM], bfr[RN];
        #pragma unroll
        for (int i = 0; i < RM; i++) af[i]  = *(const bf16x8*)&As[(wm + i * 16 + l15) * 32 + quad * 8];
        #pragma unroll
        for (int j = 0; j < RN; j++) bfr[j] = *(const bf16x8*)&Bs[(wn + j * 16 + l15) * 32 + quad * 8];
        #pragma unroll
        for (int i = 0; i < RM; i++)
            #pragma unroll
            for (int j = 0; j < RN; j++)
                acc[i][j] = __builtin_amdgcn_mfma_f32_16x16x32_bf16(af[i], bfr[j], acc[i][j], 0, 0, 0);
        __syncthreads();
    }

    // D: col(n) = lane&15, row(m) = quad*4 + r
    #pragma unroll
    for (int i = 0; i < RM; i++) {
        const int m0 = wm + i * 16 + quad * 4;
        #pragma unroll
        for (int j = 0; j < RN; j++) {
            const int n = wn + j * 16 + l15;
            #pragma unroll
            for (int r = 0; r < 4; r++) {
                const int m = m0 + r;
                if (m < mlim) {
                    if (OF32) ((float*)Cbase)[(size_t)m * DM + n] = acc[i][j][r];
                    else      ((u16*)Cbase)[(size_t)m * DM + n]   = f2bf(acc[i][j][r]);
                }
            }
        }
    }
}

__global__ __launch_bounds__(256) void gemm_qkv(const u16* __restrict__ xp, const u16* __restrict__ Wcat,
    u16* __restrict__ Qr, u16* __restrict__ Kr, u16* __restrict__ Vr)
{
    const int Mb = blockIdx.x * 64;
    const int nb = blockIdx.y;                     // 0..23 across [Wq;Wk;Wv]
    u16* C = (nb < 8) ? Qr : (nb < 16) ? Kr : Vr;
    const int Ncol = (nb & 7) * 128;
    gemm_lds<64, 128, false>(xp + (size_t)Mb * DM,
                             Wcat + (size_t)nb * 128 * DM,
                             (void*)(C + (size_t)Mb * DM + Ncol),
                             TTOT - Mb);
}

__global__ __launch_bounds__(256) void gemm_out(const u16* __restrict__ AO, const u16* __restrict__ Woh,
                                                float* __restrict__ Cout)
{
    const int Mb = blockIdx.x * 64, Nb = blockIdx.y * 128;
    gemm_lds<64, 128, true>(AO + (size_t)Mb * DM, Woh + (size_t)Nb * DM,
                            (void*)(Cout + (size_t)Mb * DM + Nb), 64);
}

// ---------------- depthwise causal conv (K=3) + bias + SiLU + optional l2norm ----------------
__global__ __launch_bounds__(256) void conv_silu_norm(
    const u16* __restrict__ Qr, const u16* __restrict__ Kr, const u16* __restrict__ Vr,
    const float* __restrict__ qw, const float* __restrict__ qb,
    const float* __restrict__ kw, const float* __restrict__ kb,
    const float* __restrict__ vw, const float* __restrict__ vb,
    u16* __restrict__ Qc, u16* __restrict__ Kc, u16* __restrict__ Vc)
{
    const int t = blockIdx.x;
    const int z = blockIdx.y;
    const u16* raw; const float *w, *b; u16* out;
    if (z == 0)      { raw = Qr; w = qw; b = qb; out = Qc; }
    else if (z == 1) { raw = Kr; w = kw; b = kb; out = Kc; }
    else             { raw = Vr; w = vw; b = vb; out = Vc; }

    const int tid = threadIdx.x;
    float vals[4];
    float ss = 0.f;
    #pragma unroll
    for (int j = 0; j < 4; j++) {
        const int d = tid + j * 256;
        float acc = b[d];
        acc += w[d*3 + 2] * bf2f(raw[(size_t)t * DM + d]);
        if (t >= 1) acc += w[d*3 + 1] * bf2f(raw[(size_t)(t-1) * DM + d]);
        if (t >= 2) acc += w[d*3 + 0] * bf2f(raw[(size_t)(t-2) * DM + d]);
        const float y = acc / (1.f + __expf(-acc));
        vals[j] = y;
        ss += y * y;
    }
    float inv = 1.f;
    if (z < 2) {
        #pragma unroll
        for (int off = 32; off > 0; off >>= 1) ss += __shfl_down(ss, off, 64);
        __shared__ float red[4];
        const int wv = tid >> 6, ln = tid & 63;
        if (ln == 0) red[wv] = ss;
        __syncthreads();
        const float tot = red[0] + red[1] + red[2] + red[3];
        inv = 1.f / fmaxf(sqrtf(tot), 1e-12f);
    }
    #pragma unroll
    for (int j = 0; j < 4; j++) {
        const int d = tid + j * 256;
        out[(size_t)t * DM + d] = f2bf(vals[j] * inv);
    }
}

// ---------------- MFMA flash attention: 1 block = 1 head x 64 queries ----------------
#define QT     64
#define KTILES 13
#define KROWS  208
#define KPAD   224
#define KSTR   72      // Ks row stride (u16)
#define VSTR   232     // Vt/Ps row stride (u16)

__global__ __launch_bounds__(256) void attn(const u16* __restrict__ Q, const u16* __restrict__ K,
                                            const u16* __restrict__ V, u16* __restrict__ AO)
{
    const int h  = blockIdx.y;
    const int qb = blockIdx.x * QT;
    const int kstart = max(NPERS, qb + NPERS - (WIN - 1));
    const int nk = NPERS + (qb + NPERS + QT - 1) - kstart + 1;   // <= 195

    // Ps (needed only after QK) overlays Ks: 64*232=14848 <= 208*72=14976
    __shared__ __align__(16) u16 KP[KROWS * KSTR];
    __shared__ __align__(16) u16 Vt[64 * VSTR];
    u16* Ks = KP;
    u16* Ps = KP;

    const int tid = threadIdx.x;

    for (int c = tid; c < KROWS * 8; c += 256) {
        const int i = c >> 3, off = (c & 7) * 8;
        if (i < nk) {
            const int g = (i < NPERS) ? i : (kstart + i - NPERS);
            *(i32x4*)&Ks[i * KSTR + off] = *(const i32x4*)&K[(size_t)g * DM + h * HDIM + off];
        }
    }
    {
        const int d = tid & 63, w4 = tid >> 6;
        for (int i2 = w4 * 2; i2 < KPAD; i2 += 8) {
            u16 a = 0, b = 0;
            if (i2 < nk)     { const int g = (i2     < NPERS) ? i2     : (kstart + i2     - NPERS); a = V[(size_t)g * DM + h * HDIM + d]; }
            if (i2 + 1 < nk) { const int g = (i2 + 1 < NPERS) ? i2 + 1 : (kstart + i2 + 1 - NPERS); b = V[(size_t)g * DM + h * HDIM + d]; }
            *(u32*)&Vt[d * VSTR + i2] = (u32)a | ((u32)b << 16);
        }
    }
    __syncthreads();

    const int wv = tid >> 6, lane = tid & 63, l15 = lane & 15, quad = lane >> 4;
    const int qloc0 = wv * 16;

    const int tqrow = qb + qloc0 + l15 + NPERS;
    const bf16x8 qa0 = *(const bf16x8*)&Q[(size_t)tqrow * DM + h * HDIM + quad * 8];
    const bf16x8 qa1 = *(const bf16x8*)&Q[(size_t)tqrow * DM + h * HDIM + 32 + quad * 8];

    f32x4 st[KTILES];
    #pragma unroll
    for (int t = 0; t < KTILES; t++) {
        const bf16x8 kb0 = *(const bf16x8*)&Ks[(t * 16 + l15) * KSTR + quad * 8];
        const bf16x8 kb1 = *(const bf16x8*)&Ks[(t * 16 + l15) * KSTR + 32 + quad * 8];
        f32x4 z = (f32x4){0.f, 0.f, 0.f, 0.f};
        z = __builtin_amdgcn_mfma_f32_16x16x32_bf16(qa0, kb0, z, 0, 0, 0);
        z = __builtin_amdgcn_mfma_f32_16x16x32_bf16(qa1, kb1, z, 0, 0, 0);
        st[t] = z;
    }

    const float scale = 0.125f;
    float mrow[4] = {-INFINITY, -INFINITY, -INFINITY, -INFINITY};
    #pragma unroll
    for (int t = 0; t < KTILES; t++) {
        const int i  = t * 16 + l15;
        const int kg = kstart + i - NPERS;
        #pragma unroll
        for (int r = 0; r < 4; r++) {
            const int tqr = qb + qloc0 + quad * 4 + r + NPERS;
            const bool ok = (i < NPERS) || ((i < nk) && (kg >= tqr - (WIN - 1)) && (kg <= tqr));
            const float s = ok ? st[t][r] * scale : -INFINITY;
            st[t][r] = s;
            mrow[r] = fmaxf(mrow[r], s);
        }
    }
    #pragma unroll
    for (int off = 1; off < 16; off <<= 1)
        #pragma unroll
        for (int r = 0; r < 4; r++) mrow[r] = fmaxf(mrow[r], __shfl_xor(mrow[r], off, 64));

    float ssum[4] = {0.f, 0.f, 0.f, 0.f};
    #pragma unroll
    for (int t = 0; t < KTILES; t++)
        #pragma unroll
        for (int r = 0; r < 4; r++) {
            const float p = __expf(st[t][r] - mrow[r]);
            st[t][r] = p;
            ssum[r] += p;
        }
    #pragma unroll
    for (int off = 1; off < 16; off <<= 1)
        #pragma unroll
        for (int r = 0; r < 4; r++) ssum[r] += __shfl_xor(ssum[r], off, 64);
    float inv[4];
    #pragma unroll
    for (int r = 0; r < 4; r++) inv[r] = 1.f / ssum[r];

    __syncthreads();   // all Ks reads done before Ps (aliased) writes

    #pragma unroll
    for (int t = 0; t < KTILES; t++)
        #pragma unroll
        for (int r = 0; r < 4; r++)
            Ps[(qloc0 + quad * 4 + r) * VSTR + t * 16 + l15] = f2bf(st[t][r] * inv[r]);
    *(u64*)&Ps[(qloc0 + l15) * VSTR + KROWS + quad * 4] = 0ULL;
    __syncthreads();

    f32x4 oacc[4];
    #pragma unroll
    for (int dt = 0; dt < 4; dt++) oacc[dt] = (f32x4){0.f, 0.f, 0.f, 0.f};
    for (int ks = 0; ks < KPAD / 32; ks++) {
        const bf16x8 pa = *(const bf16x8*)&Ps[(qloc0 + l15) * VSTR + ks * 32 + quad * 8];
        #pragma unroll
        for (int dt = 0; dt < 4; dt++) {
            const bf16x8 vb = *(const bf16x8*)&Vt[(dt * 16 + l15) * VSTR + ks * 32 + quad * 8];
            oacc[dt] = __builtin_amdgcn_mfma_f32_16x16x32_bf16(pa, vb, oacc[dt], 0, 0, 0);
        }
    }

    #pragma unroll
    for (int dt = 0; dt < 4; dt++)
        #pragma unroll
        for (int r = 0; r < 4; r++)
            AO[(size_t)(qb + qloc0 + quad * 4 + r) * DM + h * HDIM + dt * 16 + l15] = f2bf(oacc[dt][r]);
}

extern "C" void kernel_launch(void* const* d_in, const int* in_sizes, int n_in,
                              void* d_out, int out_size, void* d_ws, size_t ws_size,
                              hipStream_t stream)
{
    const float* x  = (const float*)d_in[0];
    const float* pm = (const float*)d_in[1];
    const float* Wq = (const float*)d_in[2];
    const float* Wk = (const float*)d_in[3];
    const float* Wv = (const float*)d_in[4];
    const float* Wo = (const float*)d_in[5];
    const float* qw = (const float*)d_in[6];
    const float* qb = (const float*)d_in[7];
    const float* kw = (const float*)d_in[8];
    const float* kb = (const float*)d_in[9];
    const float* vw = (const float*)d_in[10];
    const float* vb = (const float*)d_in[11];
    float* out = (float*)d_out;

    // workspace layout (u16 units), with lifetime-based aliasing (~29.5 MB)
    u16* ws16 = (u16*)d_ws;
    const size_t SZ_W  = (size_t)DM * DM;       // 1,048,576
    const size_t SZ_R  = (size_t)TTOT * DM;     // 2,101,248
    const size_t SZ_XP = (size_t)MPAD * DM;     // 2,162,688
    u16* Woh  = ws16;
    u16* Qr   = Woh + SZ_W;        u16* AO = Qr;       // AO aliases Qr (dead after conv)
    u16* Kr   = Qr + SZ_R;
    u16* Vr   = Kr + SZ_R;
    u16* Vc   = Vr + SZ_R;
    u16* xp   = Vc + SZ_R;         u16* Qc = xp;       // Qc aliases xp (dead after gemm_qkv)
    u16* Wcat = xp + SZ_XP;        u16* Kc = Wcat;     // Kc aliases Wcat

    hipLaunchKernelGGL(cvt, dim3(TTOT, 5), dim3(256), 0, stream,
                       x, pm, Wq, Wk, Wv, Wo, xp, Wcat, Woh);
    hipLaunchKernelGGL(gemm_qkv, dim3(33, 24), dim3(256), 0, stream,
                       xp, Wcat, Qr, Kr, Vr);
    hipLaunchKernelGGL(conv_silu_norm, dim3(TTOT, 3), dim3(256), 0, stream,
                       Qr, Kr, Vr, qw, qb, kw, kb, vw, vb, Qc, Kc, Vc);
    hipLaunchKernelGGL(attn, dim3(LSEQ / QT, NHEAD), dim3(256), 0, stream,
                       Qc, Kc, Vc, AO);
    hipLaunchKernelGGL(gemm_out, dim3(32, 8), dim3(256), 0, stream,
                       AO, Woh, out);
}

// Round 6
// 163.760 us; speedup vs baseline: 3.9182x; 1.0810x over previous
//
#include <hip/hip_runtime.h>
#include <math.h>

typedef unsigned short u16;
typedef unsigned int   u32;
typedef unsigned long long u64;
typedef __attribute__((ext_vector_type(8))) short bf16x8;
typedef __attribute__((ext_vector_type(4))) float f32x4;
typedef __attribute__((ext_vector_type(4))) int i32x4;

#define TTOT  2052
#define NPERS 4
#define LSEQ  2048
#define WIN   128
#define NHEAD 16
#define HDIM  64
#define DM    1024
#define MPAD  2176   // 17 * 128

__device__ __forceinline__ float bf2f(u16 u) {
    union { unsigned int i; float f; } v; v.i = ((unsigned int)u) << 16; return v.f;
}
__device__ __forceinline__ u16 f2bf(float f) {
    union { float f; unsigned int i; } v; v.f = f;
    unsigned int r = (v.i + 0x7fffu + ((v.i >> 16) & 1u)) >> 16;
    return (u16)r;
}
__device__ __forceinline__ u32 pk2(float lo, float hi) {
    return (u32)f2bf(lo) | ((u32)f2bf(hi) << 16);
}

// async global->LDS, 16B per lane; LDS dst = wave-uniform base + lane*16
__device__ __forceinline__ void glds16(const u16* g, u16* l) {
    __builtin_amdgcn_global_load_lds(
        (__attribute__((address_space(1))) void*)(g),
        (__attribute__((address_space(3))) void*)(l),
        16, 0, 0);
}

// ---------------- fp32 -> bf16 conversion / repack pass ----------------
// z=0: xp = [pm ; x] (2052 valid rows of MPAD); z=1..3: Wcat slices; z=4: Woh
__global__ __launch_bounds__(256) void cvt(const float* __restrict__ x, const float* __restrict__ pm,
    const float* __restrict__ Wq, const float* __restrict__ Wk, const float* __restrict__ Wv,
    const float* __restrict__ Wo,
    u16* __restrict__ xp, u16* __restrict__ Wcat, u16* __restrict__ Woh)
{
    const int z = blockIdx.y;
    const int u = blockIdx.x * 256 + threadIdx.x;   // unit = 4 floats
    if (z == 0) {
        if (u >= TTOT * 256) return;
        const size_t e = (size_t)u * 4;
        const int row = (int)(e >> 10), c = (int)(e & 1023);
        const float* s = (row < NPERS) ? (pm + (size_t)row * DM + c)
                                       : (x + (size_t)(row - NPERS) * DM + c);
        f32x4 v = *(const f32x4*)s;
        *(u64*)(xp + e) = (u64)pk2(v[0], v[1]) | ((u64)pk2(v[2], v[3]) << 32);
    } else {
        if (u >= 256 * DM) return;
        const size_t e = (size_t)u * 4;
        const float* s; u16* d;
        if (z == 1)      { s = Wq + e; d = Wcat + e; }
        else if (z == 2) { s = Wk + e; d = Wcat + (size_t)DM * DM + e; }
        else if (z == 3) { s = Wv + e; d = Wcat + 2 * (size_t)DM * DM + e; }
        else             { s = Wo + e; d = Woh + e; }
        f32x4 v = *(const f32x4*)s;
        *(u64*)d = (u64)pk2(v[0], v[1]) | ((u64)pk2(v[2], v[3]) << 32);
    }
}

// ---------------- m97-style bf16 GEMM: C[tile] = A * B^T, BK=32 ----------------
template<int TM, int TN, bool OF32>
__device__ __forceinline__ void gemm_lds(const u16* __restrict__ Ablk, const u16* __restrict__ Bblk,
                                         void* __restrict__ Cbase, int mlim)
{
    __shared__ __align__(16) u16 As[TM * 32];
    __shared__ __align__(16) u16 Bs[TN * 32];
    const int tid  = threadIdx.x;
    const int lane = tid & 63;
    const int l15  = lane & 15, quad = lane >> 4;
    constexpr int RM = TM / 32, RN = TN / 32;
    const int wm = (tid >> 7) * (TM / 2);
    const int wn = ((tid >> 6) & 1) * (TN / 2);
    const int wb = tid & 192;

    f32x4 acc[RM][RN];
    #pragma unroll
    for (int i = 0; i < RM; i++)
        #pragma unroll
        for (int j = 0; j < RN; j++) acc[i][j] = (f32x4){0.f, 0.f, 0.f, 0.f};

    constexpr int LA = (TM * 32) / 2048;
    constexpr int LB = (TN * 32) / 2048;

    for (int kk = 0; kk < DM; kk += 32) {
        #pragma unroll
        for (int i = 0; i < LA; i++) {
            const int e = i * 256 + tid;
            glds16(Ablk + (size_t)(e >> 2) * DM + kk + (e & 3) * 8,
                   As + (size_t)(i * 256 + wb) * 8);
        }
        #pragma unroll
        for (int i = 0; i < LB; i++) {
            const int e = i * 256 + tid;
            glds16(Bblk + (size_t)(e >> 2) * DM + kk + (e & 3) * 8,
                   Bs + (size_t)(i * 256 + wb) * 8);
        }
        __syncthreads();
        bf16x8 af[RM], bfr[RN];
        #pragma unroll
        for (int i = 0; i < RM; i++) af[i]  = *(const bf16x8*)&As[(wm + i * 16 + l15) * 32 + quad * 8];
        #pragma unroll
        for (int j = 0; j < RN; j++) bfr[j] = *(const bf16x8*)&Bs[(wn + j * 16 + l15) * 32 + quad * 8];
        #pragma unroll
        for (int i = 0; i < RM; i++)
            #pragma unroll
            for (int j = 0; j < RN; j++)
                acc[i][j] = __builtin_amdgcn_mfma_f32_16x16x32_bf16(af[i], bfr[j], acc[i][j], 0, 0, 0);
        __syncthreads();
    }

    #pragma unroll
    for (int i = 0; i < RM; i++) {
        const int m0 = wm + i * 16 + quad * 4;
        #pragma unroll
        for (int j = 0; j < RN; j++) {
            const int n = wn + j * 16 + l15;
            #pragma unroll
            for (int r = 0; r < 4; r++) {
                const int m = m0 + r;
                if (m < mlim) {
                    if (OF32) ((float*)Cbase)[(size_t)m * DM + n] = acc[i][j][r];
                    else      ((u16*)Cbase)[(size_t)m * DM + n]   = f2bf(acc[i][j][r]);
                }
            }
        }
    }
}

__global__ __launch_bounds__(256) void gemm_qkv(const u16* __restrict__ xp, const u16* __restrict__ Wcat,
    u16* __restrict__ Qr, u16* __restrict__ Kr, u16* __restrict__ Vr)
{
    const int Mb = blockIdx.x * 128;
    const int nb = blockIdx.y;                     // 0..23 across [Wq;Wk;Wv]
    u16* C = (nb < 8) ? Qr : (nb < 16) ? Kr : Vr;
    const int Ncol = (nb & 7) * 128;
    gemm_lds<128, 128, false>(xp + (size_t)Mb * DM,
                              Wcat + (size_t)nb * 128 * DM,
                              (void*)(C + (size_t)Mb * DM + Ncol),
                              TTOT - Mb);
}

__global__ __launch_bounds__(256) void gemm_out(const u16* __restrict__ AO, const u16* __restrict__ Woh,
                                                float* __restrict__ Cout)
{
    const int Mb = blockIdx.x * 64, Nb = blockIdx.y * 128;
    gemm_lds<64, 128, true>(AO + (size_t)Mb * DM, Woh + (size_t)Nb * DM,
                            (void*)(Cout + (size_t)Mb * DM + Nb), 64);
}

// ---------------- depthwise causal conv (K=3) + bias + SiLU + optional l2norm ----------------
// vectorized: 4 contiguous channels per thread (u64 bf16x4 loads, f32x4 weights)
__global__ __launch_bounds__(256) void conv_silu_norm(
    const u16* __restrict__ Qr, const u16* __restrict__ Kr, const u16* __restrict__ Vr,
    const float* __restrict__ qw, const float* __restrict__ qb,
    const float* __restrict__ kw, const float* __restrict__ kb,
    const float* __restrict__ vw, const float* __restrict__ vb,
    u16* __restrict__ Qc, u16* __restrict__ Kc, u16* __restrict__ Vc)
{
    const int t = blockIdx.x;
    const int z = blockIdx.y;
    const u16* raw; const float *w, *b; u16* out;
    if (z == 0)      { raw = Qr; w = qw; b = qb; out = Qc; }
    else if (z == 1) { raw = Kr; w = kw; b = kb; out = Kc; }
    else             { raw = Vr; w = vw; b = vb; out = Vc; }

    const int tid = threadIdx.x;
    const int d0  = tid * 4;

    const u16* r0 = raw + (size_t)t * DM + d0;
    u64 c0 = *(const u64*)r0;
    u64 c1 = (t >= 1) ? *(const u64*)(r0 - DM)     : 0ULL;
    u64 c2 = (t >= 2) ? *(const u64*)(r0 - 2 * DM) : 0ULL;
    const f32x4 bias = *(const f32x4*)(b + d0);
    const f32x4 w0v  = *(const f32x4*)(w + 3 * d0);
    const f32x4 w1v  = *(const f32x4*)(w + 3 * d0 + 4);
    const f32x4 w2v  = *(const f32x4*)(w + 3 * d0 + 8);
    const float warr[12] = {w0v[0], w0v[1], w0v[2], w0v[3],
                            w1v[0], w1v[1], w1v[2], w1v[3],
                            w2v[0], w2v[1], w2v[2], w2v[3]};

    float vals[4];
    float ss = 0.f;
    #pragma unroll
    for (int c = 0; c < 4; c++) {
        float acc = bias[c];
        acc += warr[3*c + 2] * bf2f((u16)(c0 >> (16 * c)));
        acc += warr[3*c + 1] * bf2f((u16)(c1 >> (16 * c)));
        acc += warr[3*c + 0] * bf2f((u16)(c2 >> (16 * c)));
        const float y = acc / (1.f + __expf(-acc));
        vals[c] = y;
        ss += y * y;
    }
    float inv = 1.f;
    if (z < 2) {
        #pragma unroll
        for (int off = 32; off > 0; off >>= 1) ss += __shfl_down(ss, off, 64);
        __shared__ float red[4];
        const int wv = tid >> 6, ln = tid & 63;
        if (ln == 0) red[wv] = ss;
        __syncthreads();
        const float tot = red[0] + red[1] + red[2] + red[3];
        inv = 1.f / fmaxf(sqrtf(tot), 1e-12f);
    }
    u64 o = 0;
    #pragma unroll
    for (int c = 0; c < 4; c++) o |= (u64)f2bf(vals[c] * inv) << (16 * c);
    *(u64*)(out + (size_t)t * DM + d0) = o;
}

// ---------------- MFMA flash attention: 1 block = 1 head x 64 queries ----------------
#define QT     64
#define KTILES 13
#define KROWS  208
#define KPAD   224
#define KSTR   72      // Ks row stride (u16)
#define VSTR   232     // Vt/Ps row stride (u16)

__global__ __launch_bounds__(256) void attn(const u16* __restrict__ Q, const u16* __restrict__ K,
                                            const u16* __restrict__ V, u16* __restrict__ AO)
{
    const int h  = blockIdx.y;
    const int qb = blockIdx.x * QT;
    const int kstart = max(NPERS, qb + NPERS - (WIN - 1));
    const int nk = NPERS + (qb + NPERS + QT - 1) - kstart + 1;   // <= 195

    __shared__ __align__(16) u16 KP[KROWS * KSTR];   // Ps overlays Ks after QK
    __shared__ __align__(16) u16 Vt[64 * VSTR];
    u16* Ks = KP;
    u16* Ps = KP;

    const int tid = threadIdx.x;

    for (int c = tid; c < KROWS * 8; c += 256) {
        const int i = c >> 3, off = (c & 7) * 8;
        if (i < nk) {
            const int g = (i < NPERS) ? i : (kstart + i - NPERS);
            *(i32x4*)&Ks[i * KSTR + off] = *(const i32x4*)&K[(size_t)g * DM + h * HDIM + off];
        }
    }
    {
        const int d = tid & 63, w4 = tid >> 6;
        for (int i2 = w4 * 2; i2 < KPAD; i2 += 8) {
            u16 a = 0, b = 0;
            if (i2 < nk)     { const int g = (i2     < NPERS) ? i2     : (kstart + i2     - NPERS); a = V[(size_t)g * DM + h * HDIM + d]; }
            if (i2 + 1 < nk) { const int g = (i2 + 1 < NPERS) ? i2 + 1 : (kstart + i2 + 1 - NPERS); b = V[(size_t)g * DM + h * HDIM + d]; }
            *(u32*)&Vt[d * VSTR + i2] = (u32)a | ((u32)b << 16);
        }
    }
    __syncthreads();

    const int wv = tid >> 6, lane = tid & 63, l15 = lane & 15, quad = lane >> 4;
    const int qloc0 = wv * 16;

    const int tqrow = qb + qloc0 + l15 + NPERS;
    const bf16x8 qa0 = *(const bf16x8*)&Q[(size_t)tqrow * DM + h * HDIM + quad * 8];
    const bf16x8 qa1 = *(const bf16x8*)&Q[(size_t)tqrow * DM + h * HDIM + 32 + quad * 8];

    f32x4 st[KTILES];
    #pragma unroll
    for (int t = 0; t < KTILES; t++) {
        const bf16x8 kb0 = *(const bf16x8*)&Ks[(t * 16 + l15) * KSTR + quad * 8];
        const bf16x8 kb1 = *(const bf16x8*)&Ks[(t * 16 + l15) * KSTR + 32 + quad * 8];
        f32x4 z = (f32x4){0.f, 0.f, 0.f, 0.f};
        z = __builtin_amdgcn_mfma_f32_16x16x32_bf16(qa0, kb0, z, 0, 0, 0);
        z = __builtin_amdgcn_mfma_f32_16x16x32_bf16(qa1, kb1, z, 0, 0, 0);
        st[t] = z;
    }

    const float scale = 0.125f;
    float mrow[4] = {-INFINITY, -INFINITY, -INFINITY, -INFINITY};
    #pragma unroll
    for (int t = 0; t < KTILES; t++) {
        const int i  = t * 16 + l15;
        const int kg = kstart + i - NPERS;
        #pragma unroll
        for (int r = 0; r < 4; r++) {
            const int tqr = qb + qloc0 + quad * 4 + r + NPERS;
            const bool ok = (i < NPERS) || ((i < nk) && (kg >= tqr - (WIN - 1)) && (kg <= tqr));
            const float s = ok ? st[t][r] * scale : -INFINITY;
            st[t][r] = s;
            mrow[r] = fmaxf(mrow[r], s);
        }
    }
    #pragma unroll
    for (int off = 1; off < 16; off <<= 1)
        #pragma unroll
        for (int r = 0; r < 4; r++) mrow[r] = fmaxf(mrow[r], __shfl_xor(mrow[r], off, 64));

    float ssum[4] = {0.f, 0.f, 0.f, 0.f};
    #pragma unroll
    for (int t = 0; t < KTILES; t++)
        #pragma unroll
        for (int r = 0; r < 4; r++) {
            const float p = __expf(st[t][r] - mrow[r]);
            st[t][r] = p;
            ssum[r] += p;
        }
    #pragma unroll
    for (int off = 1; off < 16; off <<= 1)
        #pragma unroll
        for (int r = 0; r < 4; r++) ssum[r] += __shfl_xor(ssum[r], off, 64);
    float inv[4];
    #pragma unroll
    for (int r = 0; r < 4; r++) inv[r] = 1.f / ssum[r];

    __syncthreads();   // all Ks reads done before Ps (aliased) writes

    #pragma unroll
    for (int t = 0; t < KTILES; t++)
        #pragma unroll
        for (int r = 0; r < 4; r++)
            Ps[(qloc0 + quad * 4 + r) * VSTR + t * 16 + l15] = f2bf(st[t][r] * inv[r]);
    *(u64*)&Ps[(qloc0 + l15) * VSTR + KROWS + quad * 4] = 0ULL;
    __syncthreads();

    f32x4 oacc[4];
    #pragma unroll
    for (int dt = 0; dt < 4; dt++) oacc[dt] = (f32x4){0.f, 0.f, 0.f, 0.f};
    for (int ks = 0; ks < KPAD / 32; ks++) {
        const bf16x8 pa = *(const bf16x8*)&Ps[(qloc0 + l15) * VSTR + ks * 32 + quad * 8];
        #pragma unroll
        for (int dt = 0; dt < 4; dt++) {
            const bf16x8 vb = *(const bf16x8*)&Vt[(dt * 16 + l15) * VSTR + ks * 32 + quad * 8];
            oacc[dt] = __builtin_amdgcn_mfma_f32_16x16x32_bf16(pa, vb, oacc[dt], 0, 0, 0);
        }
    }

    #pragma unroll
    for (int dt = 0; dt < 4; dt++)
        #pragma unroll
        for (int r = 0; r < 4; r++)
            AO[(size_t)(qb + qloc0 + quad * 4 + r) * DM + h * HDIM + dt * 16 + l15] = f2bf(oacc[dt][r]);
}

extern "C" void kernel_launch(void* const* d_in, const int* in_sizes, int n_in,
                              void* d_out, int out_size, void* d_ws, size_t ws_size,
                              hipStream_t stream)
{
    const float* x  = (const float*)d_in[0];
    const float* pm = (const float*)d_in[1];
    const float* Wq = (const float*)d_in[2];
    const float* Wk = (const float*)d_in[3];
    const float* Wv = (const float*)d_in[4];
    const float* Wo = (const float*)d_in[5];
    const float* qw = (const float*)d_in[6];
    const float* qb = (const float*)d_in[7];
    const float* kw = (const float*)d_in[8];
    const float* kb = (const float*)d_in[9];
    const float* vw = (const float*)d_in[10];
    const float* vb = (const float*)d_in[11];
    float* out = (float*)d_out;

    // workspace layout (u16 units), lifetime-based aliasing (~29.6 MB)
    u16* ws16 = (u16*)d_ws;
    const size_t SZ_W  = (size_t)DM * DM;       // 1,048,576
    const size_t SZ_R  = (size_t)TTOT * DM;     // 2,101,248
    const size_t SZ_XP = (size_t)MPAD * DM;     // 2,228,224
    u16* Woh  = ws16;
    u16* Qr   = Woh + SZ_W;        u16* AO = Qr;       // AO aliases Qr
    u16* Kr   = Qr + SZ_R;
    u16* Vr   = Kr + SZ_R;
    u16* Vc   = Vr + SZ_R;
    u16* xp   = Vc + SZ_R;         u16* Qc = xp;       // Qc aliases xp
    u16* Wcat = xp + SZ_XP;        u16* Kc = Wcat;     // Kc aliases Wcat

    hipLaunchKernelGGL(cvt, dim3(TTOT, 5), dim3(256), 0, stream,
                       x, pm, Wq, Wk, Wv, Wo, xp, Wcat, Woh);
    hipLaunchKernelGGL(gemm_qkv, dim3(17, 24), dim3(256), 0, stream,
                       xp, Wcat, Qr, Kr, Vr);
    hipLaunchKernelGGL(conv_silu_norm, dim3(TTOT, 3), dim3(256), 0, stream,
                       Qr, Kr, Vr, qw, qb, kw, kb, vw, vb, Qc, Kc, Vc);
    hipLaunchKernelGGL(attn, dim3(LSEQ / QT, NHEAD), dim3(256), 0, stream,
                       Qc, Kc, Vc, AO);
    hipLaunchKernelGGL(gemm_out, dim3(32, 8), dim3(256), 0, stream,
                       AO, Woh, out);
}

// Round 7
// 159.228 us; speedup vs baseline: 4.0297x; 1.0285x over previous
//
#include <hip/hip_runtime.h>
#include <math.h>

typedef unsigned short u16;
typedef unsigned int   u32;
typedef unsigned long long u64;
typedef __attribute__((ext_vector_type(8))) short bf16x8;
typedef __attribute__((ext_vector_type(4))) float f32x4;
typedef __attribute__((ext_vector_type(4))) int i32x4;

#define TTOT  2052
#define NPERS 4
#define LSEQ  2048
#define WIN   128
#define NHEAD 16
#define HDIM  64
#define DM    1024
#define MPAD  2176   // 17 * 128

__device__ __forceinline__ float bf2f(u16 u) {
    union { unsigned int i; float f; } v; v.i = ((unsigned int)u) << 16; return v.f;
}
__device__ __forceinline__ u16 f2bf(float f) {
    union { float f; unsigned int i; } v; v.f = f;
    unsigned int r = (v.i + 0x7fffu + ((v.i >> 16) & 1u)) >> 16;
    return (u16)r;
}
__device__ __forceinline__ u32 pk2(float lo, float hi) {
    return (u32)f2bf(lo) | ((u32)f2bf(hi) << 16);
}

// async global->LDS, 16B per lane; LDS dst = wave-uniform base + lane*16
__device__ __forceinline__ void glds16(const u16* g, u16* l) {
    __builtin_amdgcn_global_load_lds(
        (__attribute__((address_space(1))) void*)(g),
        (__attribute__((address_space(3))) void*)(l),
        16, 0, 0);
}

// ---------------- fp32 -> bf16 conversion / repack pass (exact 1D grid) ----------------
#define XP_UNITS (TTOT * DM / 4)          // 525,312  (unit = 4 floats)
#define W_UNITS  (DM * DM / 4)            // 262,144
#define CVT_BLOCKS ((XP_UNITS + 4 * W_UNITS) / 256)   // 6148 exactly

__global__ __launch_bounds__(256) void cvt(const float* __restrict__ x, const float* __restrict__ pm,
    const float* __restrict__ Wq, const float* __restrict__ Wk, const float* __restrict__ Wv,
    const float* __restrict__ Wo,
    u16* __restrict__ xp, u16* __restrict__ Wcat, u16* __restrict__ Woh)
{
    const int id = blockIdx.x * 256 + threadIdx.x;
    const float* s; u16* d;
    if (id < XP_UNITS) {
        const size_t e = (size_t)id * 4;
        const int row = (int)(e >> 10), c = (int)(e & 1023);
        s = (row < NPERS) ? (pm + (size_t)row * DM + c) : (x + (size_t)(row - NPERS) * DM + c);
        d = xp + e;
    } else {
        const int w   = id - XP_UNITS;
        const int sel = w >> 18;                     // / W_UNITS
        const size_t e = (size_t)(w & (W_UNITS - 1)) * 4;
        if (sel == 0)      { s = Wq + e; d = Wcat + e; }
        else if (sel == 1) { s = Wk + e; d = Wcat + (size_t)DM * DM + e; }
        else if (sel == 2) { s = Wv + e; d = Wcat + 2 * (size_t)DM * DM + e; }
        else               { s = Wo + e; d = Woh + e; }
    }
    f32x4 v = *(const f32x4*)s;
    *(u64*)d = (u64)pk2(v[0], v[1]) | ((u64)pk2(v[2], v[3]) << 32);
}

// ---------------- bf16 GEMM: C[tile] = A * B^T, BK=64, XOR-swizzled LDS ----------------
// LDS row = 128B = 8 chunks of 16B; chunk slot s holds global chunk (s ^ (row&7)).
// Fragment reads then hit all 8 bank-windows uniformly (b128 floor).
template<int TM, int TN, bool OF32>
__device__ __forceinline__ void gemm_lds(const u16* __restrict__ Ablk, const u16* __restrict__ Bblk,
                                         void* __restrict__ Cbase, int mlim)
{
    __shared__ __align__(16) u16 As[TM * 64];
    __shared__ __align__(16) u16 Bs[TN * 64];
    const int tid  = threadIdx.x;
    const int lane = tid & 63;
    const int l15  = lane & 15, quad = lane >> 4;
    constexpr int RM = TM / 32, RN = TN / 32;
    const int wm = (tid >> 7) * (TM / 2);
    const int wn = ((tid >> 6) & 1) * (TN / 2);

    f32x4 acc[RM][RN];
    #pragma unroll
    for (int i = 0; i < RM; i++)
        #pragma unroll
        for (int j = 0; j < RN; j++) acc[i][j] = (f32x4){0.f, 0.f, 0.f, 0.f};

    constexpr int LA = TM / 32;   // (TM*8 chunks)/256 threads
    constexpr int LB = TN / 32;

    for (int kk = 0; kk < DM; kk += 64) {
        #pragma unroll
        for (int i = 0; i < LA; i++) {
            const int e = i * 256 + tid;
            const int row = e >> 3, sc = (e & 7) ^ (row & 7);
            glds16(Ablk + (size_t)row * DM + kk + sc * 8, As + (size_t)e * 8);
        }
        #pragma unroll
        for (int i = 0; i < LB; i++) {
            const int e = i * 256 + tid;
            const int row = e >> 3, sc = (e & 7) ^ (row & 7);
            glds16(Bblk + (size_t)row * DM + kk + sc * 8, Bs + (size_t)e * 8);
        }
        __syncthreads();
        #pragma unroll
        for (int kc = 0; kc < 2; kc++) {
            bf16x8 af[RM], bfr[RN];
            #pragma unroll
            for (int i = 0; i < RM; i++)
                af[i]  = *(const bf16x8*)&As[(wm + i * 16 + l15) * 64 + (((kc * 4 + quad) ^ (l15 & 7)) * 8)];
            #pragma unroll
            for (int j = 0; j < RN; j++)
                bfr[j] = *(const bf16x8*)&Bs[(wn + j * 16 + l15) * 64 + (((kc * 4 + quad) ^ (l15 & 7)) * 8)];
            #pragma unroll
            for (int i = 0; i < RM; i++)
                #pragma unroll
                for (int j = 0; j < RN; j++)
                    acc[i][j] = __builtin_amdgcn_mfma_f32_16x16x32_bf16(af[i], bfr[j], acc[i][j], 0, 0, 0);
        }
        __syncthreads();
    }

    #pragma unroll
    for (int i = 0; i < RM; i++) {
        const int m0 = wm + i * 16 + quad * 4;
        #pragma unroll
        for (int j = 0; j < RN; j++) {
            const int n = wn + j * 16 + l15;
            #pragma unroll
            for (int r = 0; r < 4; r++) {
                const int m = m0 + r;
                if (m < mlim) {
                    if (OF32) ((float*)Cbase)[(size_t)m * DM + n] = acc[i][j][r];
                    else      ((u16*)Cbase)[(size_t)m * DM + n]   = f2bf(acc[i][j][r]);
                }
            }
        }
    }
}

__global__ __launch_bounds__(256) void gemm_qkv(const u16* __restrict__ xp, const u16* __restrict__ Wcat,
    u16* __restrict__ Qr, u16* __restrict__ Kr, u16* __restrict__ Vr)
{
    const int Mb = blockIdx.x * 128;
    const int nb = blockIdx.y;                     // 0..23 across [Wq;Wk;Wv]
    u16* C = (nb < 8) ? Qr : (nb < 16) ? Kr : Vr;
    const int Ncol = (nb & 7) * 128;
    gemm_lds<128, 128, false>(xp + (size_t)Mb * DM,
                              Wcat + (size_t)nb * 128 * DM,
                              (void*)(C + (size_t)Mb * DM + Ncol),
                              TTOT - Mb);
}

__global__ __launch_bounds__(256) void gemm_out(const u16* __restrict__ AO, const u16* __restrict__ Woh,
                                                float* __restrict__ Cout)
{
    const int Mb = blockIdx.x * 64, Nb = blockIdx.y * 128;
    gemm_lds<64, 128, true>(AO + (size_t)Mb * DM, Woh + (size_t)Nb * DM,
                            (void*)(Cout + (size_t)Mb * DM + Nb), 64);
}

// ---------------- depthwise causal conv (K=3) + bias + SiLU + optional l2norm ----------------
// 2 time-rows per block; 4 contiguous channels per thread.
__global__ __launch_bounds__(256) void conv_silu_norm(
    const u16* __restrict__ Qr, const u16* __restrict__ Kr, const u16* __restrict__ Vr,
    const float* __restrict__ qw, const float* __restrict__ qb,
    const float* __restrict__ kw, const float* __restrict__ kb,
    const float* __restrict__ vw, const float* __restrict__ vb,
    u16* __restrict__ Qc, u16* __restrict__ Kc, u16* __restrict__ Vc)
{
    const int t0 = blockIdx.x * 2;
    const int z  = blockIdx.y;
    const u16* raw; const float *w, *b; u16* out;
    if (z == 0)      { raw = Qr; w = qw; b = qb; out = Qc; }
    else if (z == 1) { raw = Kr; w = kw; b = kb; out = Kc; }
    else             { raw = Vr; w = vw; b = vb; out = Vc; }

    const int tid = threadIdx.x;
    const int d0  = tid * 4;

    const u16* r0 = raw + (size_t)t0 * DM + d0;
    const u64 cm2 = (t0 >= 2) ? *(const u64*)(r0 - 2 * DM) : 0ULL;
    const u64 cm1 = (t0 >= 1) ? *(const u64*)(r0 - DM)     : 0ULL;
    const u64 c0  = *(const u64*)r0;
    const u64 c1  = *(const u64*)(r0 + DM);
    const f32x4 bias = *(const f32x4*)(b + d0);
    const f32x4 w0v  = *(const f32x4*)(w + 3 * d0);
    const f32x4 w1v  = *(const f32x4*)(w + 3 * d0 + 4);
    const f32x4 w2v  = *(const f32x4*)(w + 3 * d0 + 8);
    const float warr[12] = {w0v[0], w0v[1], w0v[2], w0v[3],
                            w1v[0], w1v[1], w1v[2], w1v[3],
                            w2v[0], w2v[1], w2v[2], w2v[3]};

    float va[4], vb2[4];
    float ss0 = 0.f, ss1 = 0.f;
    #pragma unroll
    for (int c = 0; c < 4; c++) {
        const float xm2 = bf2f((u16)(cm2 >> (16 * c)));
        const float xm1 = bf2f((u16)(cm1 >> (16 * c)));
        const float x0  = bf2f((u16)(c0  >> (16 * c)));
        const float x1  = bf2f((u16)(c1  >> (16 * c)));
        const float w0 = warr[3*c], w1 = warr[3*c + 1], w2 = warr[3*c + 2];
        float a0 = bias[c] + w2 * x0 + w1 * xm1 + w0 * xm2;
        float a1 = bias[c] + w2 * x1 + w1 * x0  + w0 * xm1;
        const float y0 = a0 / (1.f + __expf(-a0));
        const float y1 = a1 / (1.f + __expf(-a1));
        va[c] = y0; vb2[c] = y1;
        ss0 += y0 * y0; ss1 += y1 * y1;
    }
    float inv0 = 1.f, inv1 = 1.f;
    if (z < 2) {
        #pragma unroll
        for (int off = 32; off > 0; off >>= 1) {
            ss0 += __shfl_down(ss0, off, 64);
            ss1 += __shfl_down(ss1, off, 64);
        }
        __shared__ float red[8];
        const int wv = tid >> 6, ln = tid & 63;
        if (ln == 0) { red[wv] = ss0; red[wv + 4] = ss1; }
        __syncthreads();
        inv0 = 1.f / fmaxf(sqrtf(red[0] + red[1] + red[2] + red[3]), 1e-12f);
        inv1 = 1.f / fmaxf(sqrtf(red[4] + red[5] + red[6] + red[7]), 1e-12f);
    }
    u64 o0 = 0, o1 = 0;
    #pragma unroll
    for (int c = 0; c < 4; c++) {
        o0 |= (u64)f2bf(va[c]  * inv0) << (16 * c);
        o1 |= (u64)f2bf(vb2[c] * inv1) << (16 * c);
    }
    *(u64*)(out + (size_t)t0 * DM + d0)      = o0;
    *(u64*)(out + (size_t)(t0 + 1) * DM + d0) = o1;
}

// ---------------- MFMA flash attention: 1 block = 1 head x 64 queries ----------------
#define QT     64
#define KTILES 13
#define KROWS  208
#define KPAD   224
#define KSTR   72      // Ks row stride (u16)
#define VSTR   232     // Vt/Ps row stride (u16)

__global__ __launch_bounds__(256) void attn(const u16* __restrict__ Q, const u16* __restrict__ K,
                                            const u16* __restrict__ V, u16* __restrict__ AO)
{
    const int h  = blockIdx.y;
    const int qb = blockIdx.x * QT;
    const int kstart = max(NPERS, qb + NPERS - (WIN - 1));
    const int nk = NPERS + (qb + NPERS + QT - 1) - kstart + 1;   // <= 195

    __shared__ __align__(16) u16 KP[KROWS * KSTR];   // Ps overlays Ks after QK
    __shared__ __align__(16) u16 Vt[64 * VSTR];
    u16* Ks = KP;
    u16* Ps = KP;

    const int tid = threadIdx.x;

    for (int c = tid; c < KROWS * 8; c += 256) {
        const int i = c >> 3, off = (c & 7) * 8;
        if (i < nk) {
            const int g = (i < NPERS) ? i : (kstart + i - NPERS);
            *(i32x4*)&Ks[i * KSTR + off] = *(const i32x4*)&K[(size_t)g * DM + h * HDIM + off];
        }
    }
    {
        const int d = tid & 63, w4 = tid >> 6;
        for (int i2 = w4 * 2; i2 < KPAD; i2 += 8) {
            u16 a = 0, b = 0;
            if (i2 < nk)     { const int g = (i2     < NPERS) ? i2     : (kstart + i2     - NPERS); a = V[(size_t)g * DM + h * HDIM + d]; }
            if (i2 + 1 < nk) { const int g = (i2 + 1 < NPERS) ? i2 + 1 : (kstart + i2 + 1 - NPERS); b = V[(size_t)g * DM + h * HDIM + d]; }
            *(u32*)&Vt[d * VSTR + i2] = (u32)a | ((u32)b << 16);
        }
    }
    __syncthreads();

    const int wv = tid >> 6, lane = tid & 63, l15 = lane & 15, quad = lane >> 4;
    const int qloc0 = wv * 16;

    const int tqrow = qb + qloc0 + l15 + NPERS;
    const bf16x8 qa0 = *(const bf16x8*)&Q[(size_t)tqrow * DM + h * HDIM + quad * 8];
    const bf16x8 qa1 = *(const bf16x8*)&Q[(size_t)tqrow * DM + h * HDIM + 32 + quad * 8];

    f32x4 st[KTILES];
    #pragma unroll
    for (int t = 0; t < KTILES; t++) {
        const bf16x8 kb0 = *(const bf16x8*)&Ks[(t * 16 + l15) * KSTR + quad * 8];
        const bf16x8 kb1 = *(const bf16x8*)&Ks[(t * 16 + l15) * KSTR + 32 + quad * 8];
        f32x4 z = (f32x4){0.f, 0.f, 0.f, 0.f};
        z = __builtin_amdgcn_mfma_f32_16x16x32_bf16(qa0, kb0, z, 0, 0, 0);
        z = __builtin_amdgcn_mfma_f32_16x16x32_bf16(qa1, kb1, z, 0, 0, 0);
        st[t] = z;
    }

    const float scale = 0.125f;
    float mrow[4] = {-INFINITY, -INFINITY, -INFINITY, -INFINITY};
    #pragma unroll
    for (int t = 0; t < KTILES; t++) {
        const int i  = t * 16 + l15;
        const int kg = kstart + i - NPERS;
        #pragma unroll
        for (int r = 0; r < 4; r++) {
            const int tqr = qb + qloc0 + quad * 4 + r + NPERS;
            const bool ok = (i < NPERS) || ((i < nk) && (kg >= tqr - (WIN - 1)) && (kg <= tqr));
            const float s = ok ? st[t][r] * scale : -INFINITY;
            st[t][r] = s;
            mrow[r] = fmaxf(mrow[r], s);
        }
    }
    #pragma unroll
    for (int off = 1; off < 16; off <<= 1)
        #pragma unroll
        for (int r = 0; r < 4; r++) mrow[r] = fmaxf(mrow[r], __shfl_xor(mrow[r], off, 64));

    float ssum[4] = {0.f, 0.f, 0.f, 0.f};
    #pragma unroll
    for (int t = 0; t < KTILES; t++)
        #pragma unroll
        for (int r = 0; r < 4; r++) {
            const float p = __expf(st[t][r] - mrow[r]);
            st[t][r] = p;
            ssum[r] += p;
        }
    #pragma unroll
    for (int off = 1; off < 16; off <<= 1)
        #pragma unroll
        for (int r = 0; r < 4; r++) ssum[r] += __shfl_xor(ssum[r], off, 64);
    float inv[4];
    #pragma unroll
    for (int r = 0; r < 4; r++) inv[r] = 1.f / ssum[r];

    __syncthreads();   // all Ks reads done before Ps (aliased) writes

    #pragma unroll
    for (int t = 0; t < KTILES; t++)
        #pragma unroll
        for (int r = 0; r < 4; r++)
            Ps[(qloc0 + quad * 4 + r) * VSTR + t * 16 + l15] = f2bf(st[t][r] * inv[r]);
    *(u64*)&Ps[(qloc0 + l15) * VSTR + KROWS + quad * 4] = 0ULL;
    __syncthreads();

    f32x4 oacc[4];
    #pragma unroll
    for (int dt = 0; dt < 4; dt++) oacc[dt] = (f32x4){0.f, 0.f, 0.f, 0.f};
    for (int ks = 0; ks < KPAD / 32; ks++) {
        const bf16x8 pa = *(const bf16x8*)&Ps[(qloc0 + l15) * VSTR + ks * 32 + quad * 8];
        #pragma unroll
        for (int dt = 0; dt < 4; dt++) {
            const bf16x8 vb = *(const bf16x8*)&Vt[(dt * 16 + l15) * VSTR + ks * 32 + quad * 8];
            oacc[dt] = __builtin_amdgcn_mfma_f32_16x16x32_bf16(pa, vb, oacc[dt], 0, 0, 0);
        }
    }

    #pragma unroll
    for (int dt = 0; dt < 4; dt++)
        #pragma unroll
        for (int r = 0; r < 4; r++)
            AO[(size_t)(qb + qloc0 + quad * 4 + r) * DM + h * HDIM + dt * 16 + l15] = f2bf(oacc[dt][r]);
}

extern "C" void kernel_launch(void* const* d_in, const int* in_sizes, int n_in,
                              void* d_out, int out_size, void* d_ws, size_t ws_size,
                              hipStream_t stream)
{
    const float* x  = (const float*)d_in[0];
    const float* pm = (const float*)d_in[1];
    const float* Wq = (const float*)d_in[2];
    const float* Wk = (const float*)d_in[3];
    const float* Wv = (const float*)d_in[4];
    const float* Wo = (const float*)d_in[5];
    const float* qw = (const float*)d_in[6];
    const float* qb = (const float*)d_in[7];
    const float* kw = (const float*)d_in[8];
    const float* kb = (const float*)d_in[9];
    const float* vw = (const float*)d_in[10];
    const float* vb = (const float*)d_in[11];
    float* out = (float*)d_out;

    // workspace layout (u16 units), lifetime-based aliasing (~29.6 MB)
    u16* ws16 = (u16*)d_ws;
    const size_t SZ_W  = (size_t)DM * DM;       // 1,048,576
    const size_t SZ_R  = (size_t)TTOT * DM;     // 2,101,248
    const size_t SZ_XP = (size_t)MPAD * DM;     // 2,228,224
    u16* Woh  = ws16;
    u16* Qr   = Woh + SZ_W;        u16* AO = Qr;       // AO aliases Qr
    u16* Kr   = Qr + SZ_R;
    u16* Vr   = Kr + SZ_R;
    u16* Vc   = Vr + SZ_R;
    u16* xp   = Vc + SZ_R;         u16* Qc = xp;       // Qc aliases xp
    u16* Wcat = xp + SZ_XP;        u16* Kc = Wcat;     // Kc aliases Wcat

    hipLaunchKernelGGL(cvt, dim3(CVT_BLOCKS), dim3(256), 0, stream,
                       x, pm, Wq, Wk, Wv, Wo, xp, Wcat, Woh);
    hipLaunchKernelGGL(gemm_qkv, dim3(17, 24), dim3(256), 0, stream,
                       xp, Wcat, Qr, Kr, Vr);
    hipLaunchKernelGGL(conv_silu_norm, dim3(TTOT / 2, 3), dim3(256), 0, stream,
                       Qr, Kr, Vr, qw, qb, kw, kb, vw, vb, Qc, Kc, Vc);
    hipLaunchKernelGGL(attn, dim3(LSEQ / QT, NHEAD), dim3(256), 0, stream,
                       Qc, Kc, Vc, AO);
    hipLaunchKernelGGL(gemm_out, dim3(32, 8), dim3(256), 0, stream,
                       AO, Woh, out);
}

// Round 9
// 150.826 us; speedup vs baseline: 4.2542x; 1.0557x over previous
//
#include <hip/hip_runtime.h>
#include <math.h>

typedef unsigned short u16;
typedef unsigned int   u32;
typedef unsigned long long u64;
typedef __attribute__((ext_vector_type(8))) short bf16x8;
typedef __attribute__((ext_vector_type(4))) float f32x4;
typedef __attribute__((ext_vector_type(4))) int i32x4;

#define TTOT  2052
#define NPERS 4
#define LSEQ  2048
#define WIN   128
#define NHEAD 16
#define HDIM  64
#define DM    1024
#define MPAD  2176   // 17 * 128

__device__ __forceinline__ float bf2f(u16 u) {
    union { unsigned int i; float f; } v; v.i = ((unsigned int)u) << 16; return v.f;
}
__device__ __forceinline__ u16 f2bf(float f) {
    union { float f; unsigned int i; } v; v.f = f;
    unsigned int r = (v.i + 0x7fffu + ((v.i >> 16) & 1u)) >> 16;
    return (u16)r;
}
__device__ __forceinline__ u32 pk2(float lo, float hi) {
    return (u32)f2bf(lo) | ((u32)f2bf(hi) << 16);
}

// async global->LDS, 16B per lane; LDS dst = wave-uniform base + lane*16
__device__ __forceinline__ void glds16(const u16* g, u16* l) {
    __builtin_amdgcn_global_load_lds(
        (__attribute__((address_space(1))) void*)(g),
        (__attribute__((address_space(3))) void*)(l),
        16, 0, 0);
}

// ---------------- fp32 -> bf16 conversion / repack pass (exact 1D grid) ----------------
#define XP_UNITS (TTOT * DM / 4)
#define W_UNITS  (DM * DM / 4)
#define CVT_BLOCKS ((XP_UNITS + 4 * W_UNITS) / 256)

__global__ __launch_bounds__(256) void cvt(const float* __restrict__ x, const float* __restrict__ pm,
    const float* __restrict__ Wq, const float* __restrict__ Wk, const float* __restrict__ Wv,
    const float* __restrict__ Wo,
    u16* __restrict__ xp, u16* __restrict__ Wcat, u16* __restrict__ Woh)
{
    const int id = blockIdx.x * 256 + threadIdx.x;
    const float* s; u16* d;
    if (id < XP_UNITS) {
        const size_t e = (size_t)id * 4;
        const int row = (int)(e >> 10), c = (int)(e & 1023);
        s = (row < NPERS) ? (pm + (size_t)row * DM + c) : (x + (size_t)(row - NPERS) * DM + c);
        d = xp + e;
    } else {
        const int w   = id - XP_UNITS;
        const int sel = w >> 18;
        const size_t e = (size_t)(w & (W_UNITS - 1)) * 4;
        if (sel == 0)      { s = Wq + e; d = Wcat + e; }
        else if (sel == 1) { s = Wk + e; d = Wcat + (size_t)DM * DM + e; }
        else if (sel == 2) { s = Wv + e; d = Wcat + 2 * (size_t)DM * DM + e; }
        else               { s = Wo + e; d = Woh + e; }
    }
    f32x4 v = *(const f32x4*)s;
    *(u64*)d = (u64)pk2(v[0], v[1]) | ((u64)pk2(v[2], v[3]) << 32);
}

// ---------------- bf16 GEMM: C[tile] = A * B^T, BK=64, XOR-swizzled LDS ----------------
template<int TM, int TN, bool OF32>
__device__ __forceinline__ void gemm_lds(const u16* __restrict__ Ablk, const u16* __restrict__ Bblk,
                                         void* __restrict__ Cbase, int mlim)
{
    __shared__ __align__(16) u16 As[TM * 64];
    __shared__ __align__(16) u16 Bs[TN * 64];
    const int tid  = threadIdx.x;
    const int lane = tid & 63;
    const int l15  = lane & 15, quad = lane >> 4;
    constexpr int RM = TM / 32, RN = TN / 32;
    const int wm = (tid >> 7) * (TM / 2);
    const int wn = ((tid >> 6) & 1) * (TN / 2);

    f32x4 acc[RM][RN];
    #pragma unroll
    for (int i = 0; i < RM; i++)
        #pragma unroll
        for (int j = 0; j < RN; j++) acc[i][j] = (f32x4){0.f, 0.f, 0.f, 0.f};

    constexpr int LA = TM / 32;
    constexpr int LB = TN / 32;

    for (int kk = 0; kk < DM; kk += 64) {
        #pragma unroll
        for (int i = 0; i < LA; i++) {
            const int e = i * 256 + tid;
            const int row = e >> 3, sc = (e & 7) ^ (row & 7);
            glds16(Ablk + (size_t)row * DM + kk + sc * 8, As + (size_t)e * 8);
        }
        #pragma unroll
        for (int i = 0; i < LB; i++) {
            const int e = i * 256 + tid;
            const int row = e >> 3, sc = (e & 7) ^ (row & 7);
            glds16(Bblk + (size_t)row * DM + kk + sc * 8, Bs + (size_t)e * 8);
        }
        __syncthreads();
        #pragma unroll
        for (int kc = 0; kc < 2; kc++) {
            bf16x8 af[RM], bfr[RN];
            #pragma unroll
            for (int i = 0; i < RM; i++)
                af[i]  = *(const bf16x8*)&As[(wm + i * 16 + l15) * 64 + (((kc * 4 + quad) ^ (l15 & 7)) * 8)];
            #pragma unroll
            for (int j = 0; j < RN; j++)
                bfr[j] = *(const bf16x8*)&Bs[(wn + j * 16 + l15) * 64 + (((kc * 4 + quad) ^ (l15 & 7)) * 8)];
            #pragma unroll
            for (int i = 0; i < RM; i++)
                #pragma unroll
                for (int j = 0; j < RN; j++)
                    acc[i][j] = __builtin_amdgcn_mfma_f32_16x16x32_bf16(af[i], bfr[j], acc[i][j], 0, 0, 0);
        }
        __syncthreads();
    }

    #pragma unroll
    for (int i = 0; i < RM; i++) {
        const int m0 = wm + i * 16 + quad * 4;
        #pragma unroll
        for (int j = 0; j < RN; j++) {
            const int n = wn + j * 16 + l15;
            #pragma unroll
            for (int r = 0; r < 4; r++) {
                const int m = m0 + r;
                if (m < mlim) {
                    if (OF32) ((float*)Cbase)[(size_t)m * DM + n] = acc[i][j][r];
                    else      ((u16*)Cbase)[(size_t)m * DM + n]   = f2bf(acc[i][j][r]);
                }
            }
        }
    }
}

__global__ __launch_bounds__(256) void gemm_qkv(const u16* __restrict__ xp, const u16* __restrict__ Wcat,
    u16* __restrict__ Qr, u16* __restrict__ Kr, u16* __restrict__ Vr)
{
    const int Mb = blockIdx.x * 128;
    const int nb = blockIdx.y;
    u16* C = (nb < 8) ? Qr : (nb < 16) ? Kr : Vr;
    const int Ncol = (nb & 7) * 128;
    gemm_lds<128, 128, false>(xp + (size_t)Mb * DM,
                              Wcat + (size_t)nb * 128 * DM,
                              (void*)(C + (size_t)Mb * DM + Ncol),
                              TTOT - Mb);
}

__global__ __launch_bounds__(256) void gemm_out(const u16* __restrict__ AO, const u16* __restrict__ Woh,
                                                float* __restrict__ Cout)
{
    const int Mb = blockIdx.x * 64, Nb = blockIdx.y * 128;
    gemm_lds<64, 128, true>(AO + (size_t)Mb * DM, Woh + (size_t)Nb * DM,
                            (void*)(Cout + (size_t)Mb * DM + Nb), 64);
}

// ---------------- depthwise causal conv (K=3) + bias + SiLU + optional l2norm ----------------
__global__ __launch_bounds__(256) void conv_silu_norm(
    const u16* __restrict__ Qr, const u16* __restrict__ Kr, const u16* __restrict__ Vr,
    const float* __restrict__ qw, const float* __restrict__ qb,
    const float* __restrict__ kw, const float* __restrict__ kb,
    const float* __restrict__ vw, const float* __restrict__ vb,
    u16* __restrict__ Qc, u16* __restrict__ Kc, u16* __restrict__ Vc)
{
    const int t0 = blockIdx.x * 2;
    const int z  = blockIdx.y;
    const u16* raw; const float *w, *b; u16* out;
    if (z == 0)      { raw = Qr; w = qw; b = qb; out = Qc; }
    else if (z == 1) { raw = Kr; w = kw; b = kb; out = Kc; }
    else             { raw = Vr; w = vw; b = vb; out = Vc; }

    const int tid = threadIdx.x;
    const int d0  = tid * 4;

    const u16* r0 = raw + (size_t)t0 * DM + d0;
    const u64 cm2 = (t0 >= 2) ? *(const u64*)(r0 - 2 * DM) : 0ULL;
    const u64 cm1 = (t0 >= 1) ? *(const u64*)(r0 - DM)     : 0ULL;
    const u64 c0  = *(const u64*)r0;
    const u64 c1  = *(const u64*)(r0 + DM);
    const f32x4 bias = *(const f32x4*)(b + d0);
    const f32x4 w0v  = *(const f32x4*)(w + 3 * d0);
    const f32x4 w1v  = *(const f32x4*)(w + 3 * d0 + 4);
    const f32x4 w2v  = *(const f32x4*)(w + 3 * d0 + 8);
    const float warr[12] = {w0v[0], w0v[1], w0v[2], w0v[3],
                            w1v[0], w1v[1], w1v[2], w1v[3],
                            w2v[0], w2v[1], w2v[2], w2v[3]};

    float va[4], vb2[4];
    float ss0 = 0.f, ss1 = 0.f;
    #pragma unroll
    for (int c = 0; c < 4; c++) {
        const float xm2 = bf2f((u16)(cm2 >> (16 * c)));
        const float xm1 = bf2f((u16)(cm1 >> (16 * c)));
        const float x0  = bf2f((u16)(c0  >> (16 * c)));
        const float x1  = bf2f((u16)(c1  >> (16 * c)));
        const float w0 = warr[3*c], w1 = warr[3*c + 1], w2 = warr[3*c + 2];
        float a0 = bias[c] + w2 * x0 + w1 * xm1 + w0 * xm2;
        float a1 = bias[c] + w2 * x1 + w1 * x0  + w0 * xm1;
        const float y0 = a0 / (1.f + __expf(-a0));
        const float y1 = a1 / (1.f + __expf(-a1));
        va[c] = y0; vb2[c] = y1;
        ss0 += y0 * y0; ss1 += y1 * y1;
    }
    float inv0 = 1.f, inv1 = 1.f;
    if (z < 2) {
        #pragma unroll
        for (int off = 32; off > 0; off >>= 1) {
            ss0 += __shfl_down(ss0, off, 64);
            ss1 += __shfl_down(ss1, off, 64);
        }
        __shared__ float red[8];
        const int wv = tid >> 6, ln = tid & 63;
        if (ln == 0) { red[wv] = ss0; red[wv + 4] = ss1; }
        __syncthreads();
        inv0 = 1.f / fmaxf(sqrtf(red[0] + red[1] + red[2] + red[3]), 1e-12f);
        inv1 = 1.f / fmaxf(sqrtf(red[4] + red[5] + red[6] + red[7]), 1e-12f);
    }
    u64 o0 = 0, o1 = 0;
    #pragma unroll
    for (int c = 0; c < 4; c++) {
        o0 |= (u64)f2bf(va[c]  * inv0) << (16 * c);
        o1 |= (u64)f2bf(vb2[c] * inv1) << (16 * c);
    }
    *(u64*)(out + (size_t)t0 * DM + d0)      = o0;
    *(u64*)(out + (size_t)(t0 + 1) * DM + d0) = o1;
}

// ---------------- MFMA flash attention: 1 block = 1 head x 64 queries ----------------
// Ks (stride 64, XOR-chunk-swizzled, glds16-staged) and Ps (stride VSTR) share the
// KP union region, sized for the LARGER user in u16 units:
//   Ks needs KROWS*64 = 13,312 u16; Ps needs 64*VSTR = 14,848 u16  -> KP[64*VSTR].
// V is preloaded transposed into registers (latency hidden behind K-stage + QK),
// committed to LDS after QK. Softmax needs no max-pass: ||q||,||k|| <= 1 so
// |score*scale| <= 0.125 (exp bounded; identical result).
#define QT     64
#define KTILES 13
#define KROWS  208
#define KPAD   224
#define VSTR   232     // Vt/Ps row stride (u16): 464B, 16B-aligned, 2-way banks

__global__ __launch_bounds__(256) void attn(const u16* __restrict__ Q, const u16* __restrict__ K,
                                            const u16* __restrict__ V, u16* __restrict__ AO)
{
    const int h  = blockIdx.y;
    const int qb = blockIdx.x * QT;
    const int kstart = max(NPERS, qb + NPERS - (WIN - 1));
    const int nk = NPERS + (qb + NPERS + QT - 1) - kstart + 1;   // <= 195

    __shared__ __align__(16) u16 KP[64 * VSTR];    // 29,696 B union: Ks | Ps
    __shared__ __align__(16) u16 Vt[64 * VSTR];    // 29,696 B
    u16* Ks = KP;
    u16* Ps = KP;

    const int tid  = threadIdx.x;
    const int wv   = tid >> 6, lane = tid & 63, l15 = lane & 15, quad = lane >> 4;

    // ---- issue V transposed loads into registers FIRST (overlap with K staging + QK) ----
    u32 vreg[28];
    #pragma unroll
    for (int i = 0; i < 28; i++) {
        const int i2 = wv * 2 + i * 8;
        const int g0 = (i2     < NPERS) ? i2     : min(kstart + i2     - NPERS, TTOT - 1);
        const int g1 = (i2 + 1 < NPERS) ? i2 + 1 : min(kstart + i2 + 1 - NPERS, TTOT - 1);
        vreg[i] = (u32)V[(size_t)g0 * DM + h * HDIM + lane]
                | ((u32)V[(size_t)g1 * DM + h * HDIM + lane] << 16);
    }

    // ---- stage K rows via global_load_lds, XOR-swizzled chunks ----
    #pragma unroll
    for (int i = 0; i < 7; i++) {
        const int c = i * 256 + tid;
        if (c < KROWS * 8) {
            const int r  = c >> 3;
            const int sc = (c & 7) ^ (r & 7);
            const int g  = (r < NPERS) ? r : min(kstart + r - NPERS, TTOT - 1);
            glds16(K + (size_t)g * DM + h * HDIM + sc * 8, Ks + (size_t)c * 8);
        }
    }
    __syncthreads();

    const int qloc0 = wv * 16;
    const int tqrow = qb + qloc0 + l15 + NPERS;
    const bf16x8 qa0 = *(const bf16x8*)&Q[(size_t)tqrow * DM + h * HDIM + quad * 8];
    const bf16x8 qa1 = *(const bf16x8*)&Q[(size_t)tqrow * DM + h * HDIM + 32 + quad * 8];

    const int sw = l15 & 7;
    f32x4 st[KTILES];
    #pragma unroll
    for (int t = 0; t < KTILES; t++) {
        const bf16x8 kb0 = *(const bf16x8*)&Ks[(t * 16 + l15) * 64 + ((quad ^ sw) * 8)];
        const bf16x8 kb1 = *(const bf16x8*)&Ks[(t * 16 + l15) * 64 + (((4 + quad) ^ sw) * 8)];
        f32x4 z = (f32x4){0.f, 0.f, 0.f, 0.f};
        z = __builtin_amdgcn_mfma_f32_16x16x32_bf16(qa0, kb0, z, 0, 0, 0);
        z = __builtin_amdgcn_mfma_f32_16x16x32_bf16(qa1, kb1, z, 0, 0, 0);
        st[t] = z;
    }

    // ---- masked exp (no max-pass) + row sums ----
    const float scale = 0.125f;
    float ssum[4] = {0.f, 0.f, 0.f, 0.f};
    #pragma unroll
    for (int t = 0; t < KTILES; t++) {
        const int i  = t * 16 + l15;
        const int kg = kstart + i - NPERS;
        #pragma unroll
        for (int r = 0; r < 4; r++) {
            const int tqr = qb + qloc0 + quad * 4 + r + NPERS;
            const bool ok = (i < NPERS) || ((i < nk) && (kg >= tqr - (WIN - 1)) && (kg <= tqr));
            const float p = ok ? __expf(st[t][r] * scale) : 0.f;
            st[t][r] = p;
            ssum[r] += p;
        }
    }
    #pragma unroll
    for (int off = 1; off < 16; off <<= 1)
        #pragma unroll
        for (int r = 0; r < 4; r++) ssum[r] += __shfl_xor(ssum[r], off, 64);
    float inv[4];
    #pragma unroll
    for (int r = 0; r < 4; r++) inv[r] = 1.f / ssum[r];

    __syncthreads();   // all Ks reads done before Ps (aliased) writes

    // ---- commit V registers to LDS (transposed) ----
    #pragma unroll
    for (int i = 0; i < 28; i++) {
        const int i2 = wv * 2 + i * 8;
        *(u32*)&Vt[lane * VSTR + i2] = vreg[i];
    }
    // ---- write P (bf16); zero tail keys [208,224) ----
    #pragma unroll
    for (int t = 0; t < KTILES; t++)
        #pragma unroll
        for (int r = 0; r < 4; r++)
            Ps[(qloc0 + quad * 4 + r) * VSTR + t * 16 + l15] = f2bf(st[t][r] * inv[r]);
    *(u64*)&Ps[(qloc0 + l15) * VSTR + KROWS + quad * 4] = 0ULL;
    __syncthreads();

    // ---- PV ----
    f32x4 oacc[4];
    #pragma unroll
    for (int dt = 0; dt < 4; dt++) oacc[dt] = (f32x4){0.f, 0.f, 0.f, 0.f};
    for (int ks = 0; ks < KPAD / 32; ks++) {
        const bf16x8 pa = *(const bf16x8*)&Ps[(qloc0 + l15) * VSTR + ks * 32 + quad * 8];
        #pragma unroll
        for (int dt = 0; dt < 4; dt++) {
            const bf16x8 vb = *(const bf16x8*)&Vt[(dt * 16 + l15) * VSTR + ks * 32 + quad * 8];
            oacc[dt] = __builtin_amdgcn_mfma_f32_16x16x32_bf16(pa, vb, oacc[dt], 0, 0, 0);
        }
    }

    #pragma unroll
    for (int dt = 0; dt < 4; dt++)
        #pragma unroll
        for (int r = 0; r < 4; r++)
            AO[(size_t)(qb + qloc0 + quad * 4 + r) * DM + h * HDIM + dt * 16 + l15] = f2bf(oacc[dt][r]);
}

extern "C" void kernel_launch(void* const* d_in, const int* in_sizes, int n_in,
                              void* d_out, int out_size, void* d_ws, size_t ws_size,
                              hipStream_t stream)
{
    const float* x  = (const float*)d_in[0];
    const float* pm = (const float*)d_in[1];
    const float* Wq = (const float*)d_in[2];
    const float* Wk = (const float*)d_in[3];
    const float* Wv = (const float*)d_in[4];
    const float* Wo = (const float*)d_in[5];
    const float* qw = (const float*)d_in[6];
    const float* qb = (const float*)d_in[7];
    const float* kw = (const float*)d_in[8];
    const float* kb = (const float*)d_in[9];
    const float* vw = (const float*)d_in[10];
    const float* vb = (const float*)d_in[11];
    float* out = (float*)d_out;

    u16* ws16 = (u16*)d_ws;
    const size_t SZ_W  = (size_t)DM * DM;
    const size_t SZ_R  = (size_t)TTOT * DM;
    const size_t SZ_XP = (size_t)MPAD * DM;
    u16* Woh  = ws16;
    u16* Qr   = Woh + SZ_W;        u16* AO = Qr;
    u16* Kr   = Qr + SZ_R;
    u16* Vr   = Kr + SZ_R;
    u16* Vc   = Vr + SZ_R;
    u16* xp   = Vc + SZ_R;         u16* Qc = xp;
    u16* Wcat = xp + SZ_XP;        u16* Kc = Wcat;

    hipLaunchKernelGGL(cvt, dim3(CVT_BLOCKS), dim3(256), 0, stream,
                       x, pm, Wq, Wk, Wv, Wo, xp, Wcat, Woh);
    hipLaunchKernelGGL(gemm_qkv, dim3(17, 24), dim3(256), 0, stream,
                       xp, Wcat, Qr, Kr, Vr);
    hipLaunchKernelGGL(conv_silu_norm, dim3(TTOT / 2, 3), dim3(256), 0, stream,
                       Qr, Kr, Vr, qw, qb, kw, kb, vw, vb, Qc, Kc, Vc);
    hipLaunchKernelGGL(attn, dim3(LSEQ / QT, NHEAD), dim3(256), 0, stream,
                       Qc, Kc, Vc, AO);
    hipLaunchKernelGGL(gemm_out, dim3(32, 8), dim3(256), 0, stream,
                       AO, Woh, out);
}